// Round 1
// baseline (643.037 us; speedup 1.0000x reference)
//
#include <hip/hip_runtime.h>
#include <math.h>

static __device__ __forceinline__ float eluf(float x) {
    return x > 0.0f ? x : expm1f(x);
}

// ---------------------------------------------------------------------------
// Generic tiled GEMM-BT: C[m,n] = sum_k A[m*lda+k] * B[n*ldb+k]
// grid: (N/64, M/64, ksplit); block 256. C += bz*strideCz, k in [bz*kchunk, ...)
// Raw output (no bias/act) — consumers fold bias+relu on load.
// ---------------------------------------------------------------------------
__global__ __launch_bounds__(256) void gemm_bt(
    const float* __restrict__ A, int lda,
    const float* __restrict__ B, int ldb,
    float* __restrict__ C, int ldc, long strideCz,
    int K, int kchunk)
{
    __shared__ __align__(16) float As[16 * 68];
    __shared__ __align__(16) float Bs[16 * 68];
    const int t  = threadIdx.x;
    const int tx = t & 15, ty = t >> 4;
    const int n0 = blockIdx.x * 64, m0 = blockIdx.y * 64;
    const int kb0  = blockIdx.z * kchunk;
    const int kend = min(K, kb0 + kchunk);
    C += (long)blockIdx.z * strideCz;

    float acc[4][4] = {};
    for (int kb = kb0; kb < kend; kb += 16) {
        #pragma unroll
        for (int q = 0; q < 4; ++q) {
            int idx = t + q * 256;
            int m = idx >> 4, kk = idx & 15;
            int k = kb + kk;
            As[kk * 68 + m] = (k < kend) ? A[(long)(m0 + m) * lda + k] : 0.0f;
            Bs[kk * 68 + m] = (k < kend) ? B[(long)(n0 + m) * ldb + k] : 0.0f;
        }
        __syncthreads();
        #pragma unroll
        for (int kk = 0; kk < 16; ++kk) {
            float4 a4 = *reinterpret_cast<const float4*>(&As[kk * 68 + ty * 4]);
            float4 b4 = *reinterpret_cast<const float4*>(&Bs[kk * 68 + tx * 4]);
            float aa[4] = {a4.x, a4.y, a4.z, a4.w};
            float bb[4] = {b4.x, b4.y, b4.z, b4.w};
            #pragma unroll
            for (int i = 0; i < 4; ++i)
                #pragma unroll
                for (int j = 0; j < 4; ++j)
                    acc[i][j] += aa[i] * bb[j];
        }
        __syncthreads();
    }
    #pragma unroll
    for (int i = 0; i < 4; ++i) {
        float4 st = make_float4(acc[i][0], acc[i][1], acc[i][2], acc[i][3]);
        *reinterpret_cast<float4*>(&C[(long)(m0 + ty * 4 + i) * ldc + n0 + tx * 4]) = st;
    }
}

// dst[i] = act( sum_j src[i + j*pstride] + bias[i % biasMod] )
__global__ __launch_bounds__(256) void reduce_partials(
    const float* __restrict__ src, float* __restrict__ dst, int n,
    int nparts, long pstride, const float* __restrict__ bias, int biasMod, int doRelu)
{
    int i = blockIdx.x * 256 + threadIdx.x;
    if (i >= n) return;
    float a = 0.0f;
    for (int j = 0; j < nparts; ++j) a += src[i + (long)j * pstride];
    if (bias) a += bias[i % biasMod];
    if (doRelu) a = fmaxf(a, 0.0f);
    dst[i] = a;
}

// ---------------------------------------------------------------------------
// Coef pipeline part 1: per (x,y) pair -> cfs[x,y,0:32]
// block = 64 threads (1 wave), grid = 4096
// ---------------------------------------------------------------------------
__global__ __launch_bounds__(64) void coef_kernel(
    const float* __restrict__ coef_m,   // [64,64,8]
    const float* __restrict__ cW,       // [8,32]  (coef_nn_W[:,:,0])
    const float* __restrict__ cB,       // [8,32]
    const float* __restrict__ attW,     // [8,32,32]  (f,g,h)
    float* __restrict__ cfs)            // [64,64,32]
{
    __shared__ float cf_s[256];
    __shared__ float part[64];
    const int t  = threadIdx.x;
    const int xy = blockIdx.x;
    float ls = 0.0f;
    #pragma unroll
    for (int i = 0; i < 4; ++i) {
        int idx = i * 64 + t;
        int f = idx >> 5;
        float v = eluf(coef_m[xy * 8 + f] * cW[idx] + cB[idx]);
        cf_s[idx] = v;
        ls += expf(eluf(v));
    }
    #pragma unroll
    for (int m = 1; m < 64; m <<= 1) ls += __shfl_xor(ls, m, 64);
    __syncthreads();
    const float s = ls;
    const int g = t & 31, fg = t >> 5;
    float acc = 0.0f;
    for (int f = fg * 4; f < fg * 4 + 4; ++f) {
        float lin = 0.0f;
        for (int h = 0; h < 32; ++h)
            lin += cf_s[f * 32 + h] * attW[f * 1024 + g * 32 + h];
        float e = expf(eluf(cf_s[f * 32 + g]));
        acc += eluf(e * lin / s);
    }
    part[t] = acc;
    __syncthreads();
    if (t < 32) {
        float tot = part[t] + part[t + 32];
        cfs[xy * 32 + t] = eluf(tot * 0.125f);
    }
}

// ---------------------------------------------------------------------------
// Coef pipeline part 2: node attention -> att[o, i*32+g], grid = 64, block 256
// ---------------------------------------------------------------------------
__global__ __launch_bounds__(256) void att_kernel(
    const float* __restrict__ cfs,     // [64,64,32]
    const float* __restrict__ oattW,   // [64,32,32] (i,g,h)
    float* __restrict__ att)           // [64,2048]
{
    __shared__ float L[2048];
    __shared__ float red[256];
    __shared__ float csum[32];
    const int t = threadIdx.x;
    const int o = blockIdx.x;
    #pragma unroll
    for (int j = 0; j < 8; ++j) L[t + 256 * j] = cfs[o * 2048 + t + 256 * j];
    __syncthreads();
    {
        int h = t & 31, ig = t >> 5;
        float ps = 0.0f;
        for (int i = ig * 8; i < ig * 8 + 8; ++i) ps += expf(eluf(L[i * 32 + h]));
        red[t] = ps;
        __syncthreads();
        if (t < 32) {
            float cs = 0.0f;
            #pragma unroll
            for (int j = 0; j < 8; ++j) cs += red[t + 32 * j];
            csum[t] = cs;
        }
        __syncthreads();
    }
    #pragma unroll
    for (int j = 0; j < 8; ++j) {
        int idx = t + 256 * j;
        int i = idx >> 5, g = idx & 31;
        float lin2 = 0.0f;
        for (int h = 0; h < 32; ++h)
            lin2 += L[i * 32 + h] * oattW[i * 1024 + g * 32 + h];
        float p2 = expf(eluf(L[idx])) / csum[g];
        att[o * 2048 + idx] = p2 * lin2;
    }
}

// natt[o,d] = sum_p ntW[o,p] * att[p,d]   grid 64, block 256
__global__ __launch_bounds__(256) void natt_kernel(
    const float* __restrict__ ntW,   // [64,64]
    const float* __restrict__ att,   // [64,2048]
    float* __restrict__ natt)        // [64,2048]
{
    __shared__ float w[64];
    const int t = threadIdx.x;
    const int o = blockIdx.x;
    if (t < 64) w[t] = ntW[o * 64 + t];
    __syncthreads();
    for (int j = t; j < 2048; j += 256) {
        float acc = 0.0f;
        for (int p = 0; p < 64; ++p) acc += w[p] * att[p * 2048 + j];
        natt[o * 2048 + j] = acc;
    }
}

// ---------------------------------------------------------------------------
// nt1[b*64+o, d] = sum_p ntW[o,p] * relu(h3[b, p*64+d] + out1_b[p*64+d])
// grid 512 (b), block 256
// ---------------------------------------------------------------------------
__global__ __launch_bounds__(256) void nt1_kernel(
    const float* __restrict__ h3,     // [512,4096] raw (pre-bias/relu)
    const float* __restrict__ out1b,  // [4096]
    const float* __restrict__ ntW,    // [64,64]
    float* __restrict__ nt1)          // [32768,64]
{
    __shared__ __align__(16) float WsT[64 * 68];  // [p][o]
    __shared__ __align__(16) float Hb[64 * 68];   // [p][d]
    const int t = threadIdx.x;
    const int b = blockIdx.x;
    #pragma unroll
    for (int j = 0; j < 16; ++j) {
        int idx = t + 256 * j;
        int r = idx >> 6, cidx = idx & 63;
        WsT[cidx * 68 + r] = ntW[idx];                      // idx = o*64+p
        float v = h3[(long)b * 4096 + idx] + out1b[idx];    // idx = p*64+d
        Hb[r * 68 + cidx] = fmaxf(v, 0.0f);
    }
    __syncthreads();
    const int td = t & 15, to = t >> 4;
    float acc[4][4] = {};
    for (int p = 0; p < 64; ++p) {
        float4 w4 = *reinterpret_cast<const float4*>(&WsT[p * 68 + to * 4]);
        float4 h4 = *reinterpret_cast<const float4*>(&Hb[p * 68 + td * 4]);
        float wa[4] = {w4.x, w4.y, w4.z, w4.w};
        float ha[4] = {h4.x, h4.y, h4.z, h4.w};
        #pragma unroll
        for (int i = 0; i < 4; ++i)
            #pragma unroll
            for (int j = 0; j < 4; ++j)
                acc[i][j] += wa[i] * ha[j];
    }
    #pragma unroll
    for (int i = 0; i < 4; ++i) {
        float4 st = make_float4(acc[i][0], acc[i][1], acc[i][2], acc[i][3]);
        *reinterpret_cast<float4*>(&nt1[((long)b * 64 + to * 4 + i) * 64 + td * 4]) = st;
    }
}

// ---------------------------------------------------------------------------
// Final fused kernel:
// z[b,o] = prelu( sum_e sigmoid( dot64(nt1[b*64+o,:], G[e,0:64]) + c[o,e] ) * w[e] + bias )
// grid 512 (b), block 256 = 16(te) x 16(to); e-chunks of 64, 33 chunks (2112)
// ---------------------------------------------------------------------------
__global__ __launch_bounds__(256) void final_kernel(
    const float* __restrict__ nt1,    // [32768,64]
    const float* __restrict__ tgw,    // [2112,2112]
    const float* __restrict__ cmat,   // [64,2112]
    const float* __restrict__ outW,   // [2112]
    const float* __restrict__ outB,   // [1]
    const float* __restrict__ preluA, // [1]
    float* __restrict__ out)          // [512,64]
{
    __shared__ __align__(16) float At[64 * 68];  // [k][o]
    __shared__ __align__(16) float Gt[64 * 68];  // [k][ee]
    const int t = threadIdx.x;
    const int b = blockIdx.x;
    const int te = t & 15, to = t >> 4;
    #pragma unroll
    for (int j = 0; j < 16; ++j) {
        int idx = t + 256 * j;
        int o = idx >> 6, k = idx & 63;
        At[k * 68 + o] = nt1[(long)b * 4096 + idx];
    }
    float zacc[4] = {0.0f, 0.0f, 0.0f, 0.0f};
    for (int ec = 0; ec < 33; ++ec) {
        const int e0 = ec * 64;
        __syncthreads();   // protects Gt rewrite (and At staging at ec=0)
        #pragma unroll
        for (int j = 0; j < 16; ++j) {
            int idx = t + 256 * j;
            int ee = idx >> 6, k = idx & 63;
            Gt[k * 68 + ee] = tgw[(long)(e0 + ee) * 2112 + k];
        }
        __syncthreads();
        float S[4][4];
        #pragma unroll
        for (int i = 0; i < 4; ++i) {
            float4 c4 = *reinterpret_cast<const float4*>(
                &cmat[(to * 4 + i) * 2112 + e0 + te * 4]);
            S[i][0] = c4.x; S[i][1] = c4.y; S[i][2] = c4.z; S[i][3] = c4.w;
        }
        for (int k = 0; k < 64; ++k) {
            float4 a4 = *reinterpret_cast<const float4*>(&At[k * 68 + to * 4]);
            float4 g4 = *reinterpret_cast<const float4*>(&Gt[k * 68 + te * 4]);
            float aa[4] = {a4.x, a4.y, a4.z, a4.w};
            float gg[4] = {g4.x, g4.y, g4.z, g4.w};
            #pragma unroll
            for (int i = 0; i < 4; ++i)
                #pragma unroll
                for (int j = 0; j < 4; ++j)
                    S[i][j] += aa[i] * gg[j];
        }
        float4 w4 = *reinterpret_cast<const float4*>(&outW[e0 + te * 4]);
        float ww[4] = {w4.x, w4.y, w4.z, w4.w};
        #pragma unroll
        for (int i = 0; i < 4; ++i)
            #pragma unroll
            for (int j = 0; j < 4; ++j) {
                float sg = 1.0f / (1.0f + expf(-S[i][j]));
                zacc[i] += sg * ww[j];
            }
    }
    #pragma unroll
    for (int m = 1; m < 16; m <<= 1)
        #pragma unroll
        for (int i = 0; i < 4; ++i) zacc[i] += __shfl_xor(zacc[i], m, 64);
    if (te == 0) {
        const float bo = outB[0], pa = preluA[0];
        #pragma unroll
        for (int i = 0; i < 4; ++i) {
            float z = zacc[i] + bo;
            out[b * 64 + to * 4 + i] = (z >= 0.0f) ? z : pa * z;
        }
    }
}

extern "C" void kernel_launch(void* const* d_in, const int* in_sizes, int n_in,
                              void* d_out, int out_size, void* d_ws, size_t ws_size,
                              hipStream_t stream)
{
    const float* x       = (const float*)d_in[0];
    const float* fc_in_W = (const float*)d_in[1];
    const float* fc_in_b = (const float*)d_in[2];
    const float* fc1_W   = (const float*)d_in[3];
    const float* fc1_b   = (const float*)d_in[4];
    const float* out1_W  = (const float*)d_in[5];
    const float* out1_b  = (const float*)d_in[6];
    const float* cW      = (const float*)d_in[7];
    const float* cB      = (const float*)d_in[8];
    const float* cattW   = (const float*)d_in[9];
    const float* oattW   = (const float*)d_in[10];
    const float* ntW     = (const float*)d_in[11];
    const float* tgw     = (const float*)d_in[12];
    const float* outW    = (const float*)d_in[13];
    const float* outB    = (const float*)d_in[14];
    const float* preluA  = (const float*)d_in[15];
    const float* coef_m  = (const float*)d_in[16];
    float* out = (float*)d_out;
    float* ws  = (float*)d_ws;

    // workspace layout (floats)
    float* h1p  = ws;             // 2*524288
    float* h1   = ws + 1048576;   // 524288
    float* h2p  = ws + 1572864;   // 8*65536
    float* h2   = ws + 2097152;   // 65536
    float* h3   = ws + 2162688;   // 2097152 (512x4096, raw)
    float* cfs  = ws + 4259840;   // 131072
    float* att  = ws + 4390912;   // 131072
    float* natt = ws + 4521984;   // 131072
    float* cp   = ws + 4653056;   // 8*135168
    float* cmat = ws + 5734400;   // 135168
    float* nt1  = ws + 5869568;   // 2097152
    // total 7,966,720 floats (~31.9 MB)

    // trunk MLP
    gemm_bt<<<dim3(16, 8, 2), 256, 0, stream>>>(x, 2000, fc_in_W, 2000,
                                                h1p, 1024, 524288L, 2000, 1000);
    reduce_partials<<<2048, 256, 0, stream>>>(h1p, h1, 524288, 2, 524288L,
                                              fc_in_b, 1024, 1);
    gemm_bt<<<dim3(2, 8, 8), 256, 0, stream>>>(h1, 1024, fc1_W, 1024,
                                               h2p, 128, 65536L, 1024, 128);
    reduce_partials<<<256, 256, 0, stream>>>(h2p, h2, 65536, 8, 65536L,
                                             fc1_b, 128, 1);
    gemm_bt<<<dim3(64, 8, 1), 256, 0, stream>>>(h2, 128, out1_W, 128,
                                                h3, 4096, 0L, 128, 128);

    // batch-independent attention-coefficient path
    coef_kernel<<<4096, 64, 0, stream>>>(coef_m, cW, cB, cattW, cfs);
    att_kernel<<<64, 256, 0, stream>>>(cfs, oattW, att);
    natt_kernel<<<64, 256, 0, stream>>>(ntW, att, natt);
    // c[o,e] = sum_{d<2048} natt[o,d] * tgw[e, 64+d]
    gemm_bt<<<dim3(33, 1, 8), 256, 0, stream>>>(natt, 2048, tgw + 64, 2112,
                                                cp, 2112, 135168L, 2048, 256);
    reduce_partials<<<528, 256, 0, stream>>>(cp, cmat, 135168, 8, 135168L,
                                             nullptr, 1, 0);

    // batch-dependent node mixing + fused final
    nt1_kernel<<<512, 256, 0, stream>>>(h3, out1_b, ntW, nt1);
    final_kernel<<<512, 256, 0, stream>>>(nt1, tgw, cmat, outW, outB, preluA, out);
}

// Round 2
// 452.261 us; speedup vs baseline: 1.4218x; 1.4218x over previous
//
#include <hip/hip_runtime.h>
#include <math.h>

typedef __attribute__((ext_vector_type(8))) short bf16x8;
typedef __attribute__((ext_vector_type(4))) float f32x4;

static __device__ __forceinline__ float eluf(float x) {
    return x > 0.0f ? x : expm1f(x);
}

static __device__ __forceinline__ unsigned short f2bf(float f) {
    unsigned int u = __float_as_uint(f);
    unsigned int r = (u + 0x7FFFu + ((u >> 16) & 1u)) >> 16;
    return (unsigned short)r;
}

// ---------------------------------------------------------------------------
// Generic tiled GEMM-BT: C[m,n] = sum_k A[m*lda+k] * B[n*ldb+k]
// grid: (N/64, M/64, ksplit); block 256. C += bz*strideCz, k in [bz*kchunk, ...)
// ---------------------------------------------------------------------------
__global__ __launch_bounds__(256) void gemm_bt(
    const float* __restrict__ A, int lda,
    const float* __restrict__ B, int ldb,
    float* __restrict__ C, int ldc, long strideCz,
    int K, int kchunk)
{
    __shared__ __align__(16) float As[16 * 68];
    __shared__ __align__(16) float Bs[16 * 68];
    const int t  = threadIdx.x;
    const int tx = t & 15, ty = t >> 4;
    const int n0 = blockIdx.x * 64, m0 = blockIdx.y * 64;
    const int kb0  = blockIdx.z * kchunk;
    const int kend = min(K, kb0 + kchunk);
    C += (long)blockIdx.z * strideCz;

    float acc[4][4] = {};
    for (int kb = kb0; kb < kend; kb += 16) {
        #pragma unroll
        for (int q = 0; q < 4; ++q) {
            int idx = t + q * 256;
            int m = idx >> 4, kk = idx & 15;
            int k = kb + kk;
            As[kk * 68 + m] = (k < kend) ? A[(long)(m0 + m) * lda + k] : 0.0f;
            Bs[kk * 68 + m] = (k < kend) ? B[(long)(n0 + m) * ldb + k] : 0.0f;
        }
        __syncthreads();
        #pragma unroll
        for (int kk = 0; kk < 16; ++kk) {
            float4 a4 = *reinterpret_cast<const float4*>(&As[kk * 68 + ty * 4]);
            float4 b4 = *reinterpret_cast<const float4*>(&Bs[kk * 68 + tx * 4]);
            float aa[4] = {a4.x, a4.y, a4.z, a4.w};
            float bb[4] = {b4.x, b4.y, b4.z, b4.w};
            #pragma unroll
            for (int i = 0; i < 4; ++i)
                #pragma unroll
                for (int j = 0; j < 4; ++j)
                    acc[i][j] += aa[i] * bb[j];
        }
        __syncthreads();
    }
    #pragma unroll
    for (int i = 0; i < 4; ++i) {
        float4 st = make_float4(acc[i][0], acc[i][1], acc[i][2], acc[i][3]);
        *reinterpret_cast<float4*>(&C[(long)(m0 + ty * 4 + i) * ldc + n0 + tx * 4]) = st;
    }
}

// dst[i] = act( sum_j src[i + j*pstride] + bias[i % biasMod] )
__global__ __launch_bounds__(256) void reduce_partials(
    const float* __restrict__ src, float* __restrict__ dst, int n,
    int nparts, long pstride, const float* __restrict__ bias, int biasMod, int doRelu)
{
    int i = blockIdx.x * 256 + threadIdx.x;
    if (i >= n) return;
    float a = 0.0f;
    for (int j = 0; j < nparts; ++j) a += src[i + (long)j * pstride];
    if (bias) a += bias[i % biasMod];
    if (doRelu) a = fmaxf(a, 0.0f);
    dst[i] = a;
}

// bf16 copy of tgw[:, 0:64]: Gb[e*64+k] = bf16(tgw[e*2112+k])
__global__ __launch_bounds__(256) void conv_g(
    const float* __restrict__ tgw, unsigned short* __restrict__ Gb)
{
    int i = blockIdx.x * 256 + threadIdx.x;  // < 135168
    int e = i >> 6, k = i & 63;
    Gb[i] = f2bf(tgw[(long)e * 2112 + k]);
}

// ---------------------------------------------------------------------------
// Coef pipeline part 1: per (x,y) pair -> cfs[x,y,0:32]
// ---------------------------------------------------------------------------
__global__ __launch_bounds__(64) void coef_kernel(
    const float* __restrict__ coef_m,   // [64,64,8]
    const float* __restrict__ cW,       // [8,32]
    const float* __restrict__ cB,       // [8,32]
    const float* __restrict__ attW,     // [8,32,32]
    float* __restrict__ cfs)            // [64,64,32]
{
    __shared__ float cf_s[256];
    __shared__ float part[64];
    const int t  = threadIdx.x;
    const int xy = blockIdx.x;
    float ls = 0.0f;
    #pragma unroll
    for (int i = 0; i < 4; ++i) {
        int idx = i * 64 + t;
        int f = idx >> 5;
        float v = eluf(coef_m[xy * 8 + f] * cW[idx] + cB[idx]);
        cf_s[idx] = v;
        ls += expf(eluf(v));
    }
    #pragma unroll
    for (int m = 1; m < 64; m <<= 1) ls += __shfl_xor(ls, m, 64);
    __syncthreads();
    const float s = ls;
    const int g = t & 31, fg = t >> 5;
    float acc = 0.0f;
    for (int f = fg * 4; f < fg * 4 + 4; ++f) {
        float lin = 0.0f;
        for (int h = 0; h < 32; ++h)
            lin += cf_s[f * 32 + h] * attW[f * 1024 + g * 32 + h];
        float e = expf(eluf(cf_s[f * 32 + g]));
        acc += eluf(e * lin / s);
    }
    part[t] = acc;
    __syncthreads();
    if (t < 32) {
        float tot = part[t] + part[t + 32];
        cfs[xy * 32 + t] = eluf(tot * 0.125f);
    }
}

// ---------------------------------------------------------------------------
// Coef pipeline part 2: node attention -> att[o, i*32+g]
// ---------------------------------------------------------------------------
__global__ __launch_bounds__(256) void att_kernel(
    const float* __restrict__ cfs,     // [64,64,32]
    const float* __restrict__ oattW,   // [64,32,32]
    float* __restrict__ att)           // [64,2048]
{
    __shared__ float L[2048];
    __shared__ float red[256];
    __shared__ float csum[32];
    const int t = threadIdx.x;
    const int o = blockIdx.x;
    #pragma unroll
    for (int j = 0; j < 8; ++j) L[t + 256 * j] = cfs[o * 2048 + t + 256 * j];
    __syncthreads();
    {
        int h = t & 31, ig = t >> 5;
        float ps = 0.0f;
        for (int i = ig * 8; i < ig * 8 + 8; ++i) ps += expf(eluf(L[i * 32 + h]));
        red[t] = ps;
        __syncthreads();
        if (t < 32) {
            float cs = 0.0f;
            #pragma unroll
            for (int j = 0; j < 8; ++j) cs += red[t + 32 * j];
            csum[t] = cs;
        }
        __syncthreads();
    }
    #pragma unroll
    for (int j = 0; j < 8; ++j) {
        int idx = t + 256 * j;
        int i = idx >> 5, g = idx & 31;
        float lin2 = 0.0f;
        for (int h = 0; h < 32; ++h)
            lin2 += L[i * 32 + h] * oattW[i * 1024 + g * 32 + h];
        float p2 = expf(eluf(L[idx])) / csum[g];
        att[o * 2048 + idx] = p2 * lin2;
    }
}

// natt[o,d] = sum_p ntW[o,p] * att[p,d]
__global__ __launch_bounds__(256) void natt_kernel(
    const float* __restrict__ ntW,   // [64,64]
    const float* __restrict__ att,   // [64,2048]
    float* __restrict__ natt)        // [64,2048]
{
    __shared__ float w[64];
    const int t = threadIdx.x;
    const int o = blockIdx.x;
    if (t < 64) w[t] = ntW[o * 64 + t];
    __syncthreads();
    for (int j = t; j < 2048; j += 256) {
        float acc = 0.0f;
        for (int p = 0; p < 64; ++p) acc += w[p] * att[p * 2048 + j];
        natt[o * 2048 + j] = acc;
    }
}

// ---------------------------------------------------------------------------
// nt1b[b*64+o, d] = bf16( sum_p ntW[o,p] * relu(h3[b, p*64+d] + out1_b[p*64+d]) )
// ---------------------------------------------------------------------------
__global__ __launch_bounds__(256) void nt1_kernel(
    const float* __restrict__ h3,     // [512,4096] raw (pre-bias/relu)
    const float* __restrict__ out1b,  // [4096]
    const float* __restrict__ ntW,    // [64,64]
    unsigned short* __restrict__ nt1b) // [32768,64] bf16
{
    __shared__ __align__(16) float WsT[64 * 68];  // [p][o]
    __shared__ __align__(16) float Hb[64 * 68];   // [p][d]
    const int t = threadIdx.x;
    const int b = blockIdx.x;
    #pragma unroll
    for (int j = 0; j < 16; ++j) {
        int idx = t + 256 * j;
        int r = idx >> 6, cidx = idx & 63;
        WsT[cidx * 68 + r] = ntW[idx];                      // idx = o*64+p
        float v = h3[(long)b * 4096 + idx] + out1b[idx];    // idx = p*64+d
        Hb[r * 68 + cidx] = fmaxf(v, 0.0f);
    }
    __syncthreads();
    const int td = t & 15, to = t >> 4;
    float acc[4][4] = {};
    for (int p = 0; p < 64; ++p) {
        float4 w4 = *reinterpret_cast<const float4*>(&WsT[p * 68 + to * 4]);
        float4 h4 = *reinterpret_cast<const float4*>(&Hb[p * 68 + td * 4]);
        float wa[4] = {w4.x, w4.y, w4.z, w4.w};
        float ha[4] = {h4.x, h4.y, h4.z, h4.w};
        #pragma unroll
        for (int i = 0; i < 4; ++i)
            #pragma unroll
            for (int j = 0; j < 4; ++j)
                acc[i][j] += wa[i] * ha[j];
    }
    #pragma unroll
    for (int i = 0; i < 4; ++i) {
        ushort4 st;
        st.x = f2bf(acc[i][0]); st.y = f2bf(acc[i][1]);
        st.z = f2bf(acc[i][2]); st.w = f2bf(acc[i][3]);
        *reinterpret_cast<ushort4*>(
            &nt1b[((long)b * 64 + to * 4 + i) * 64 + td * 4]) = st;
    }
}

// ---------------------------------------------------------------------------
// Final fused kernel (MFMA):
// z[b,o] = prelu( sum_e sigmoid( dot64_bf16(nt1[b,o,:], G[e,:]) + c[o,e] ) * w[e] + b )
// grid 512 (b); block 256 = 4 waves; wave w owns e-slice [ec*64+16w, +16).
// A-fragments held in registers across all 33 e-chunks; B streams from L2.
// ---------------------------------------------------------------------------
__global__ __launch_bounds__(256) void final_mfma(
    const unsigned short* __restrict__ nt1b, // [32768,64] bf16
    const unsigned short* __restrict__ Gb,   // [2112,64] bf16
    const float* __restrict__ cmat,   // [64,2112]
    const float* __restrict__ outW,   // [2112]
    const float* __restrict__ outB,   // [1]
    const float* __restrict__ preluA, // [1]
    float* __restrict__ out)          // [512,64]
{
    const int t = threadIdx.x;
    const int w = t >> 6;
    const int lane = t & 63;
    const int l16 = lane & 15, quad = lane >> 4;
    const int b = blockIdx.x;

    // A fragments: afr[ot][h] covers o in [16*ot,16*ot+16), k in [32h,32h+32)
    // layout: A[m = lane&15][k = quad*8 + j]
    bf16x8 afr[4][2];
    const unsigned short* Abase = nt1b + (long)b * 4096;
    #pragma unroll
    for (int ot = 0; ot < 4; ++ot)
        #pragma unroll
        for (int h = 0; h < 2; ++h)
            afr[ot][h] = *reinterpret_cast<const bf16x8*>(
                Abase + (ot * 16 + l16) * 64 + h * 32 + quad * 8);

    float zacc[4][4] = {};  // [ot][i] -> o = ot*16 + quad*4 + i
    for (int ec = 0; ec < 33; ++ec) {
        const int e = ec * 64 + w * 16 + l16;
        bf16x8 bfr0 = *reinterpret_cast<const bf16x8*>(Gb + (long)e * 64 + quad * 8);
        bf16x8 bfr1 = *reinterpret_cast<const bf16x8*>(Gb + (long)e * 64 + 32 + quad * 8);
        const float wv = outW[e];
        #pragma unroll
        for (int ot = 0; ot < 4; ++ot) {
            f32x4 acc = {0.0f, 0.0f, 0.0f, 0.0f};
            acc = __builtin_amdgcn_mfma_f32_16x16x32_bf16(afr[ot][0], bfr0, acc, 0, 0, 0);
            acc = __builtin_amdgcn_mfma_f32_16x16x32_bf16(afr[ot][1], bfr1, acc, 0, 0, 0);
            #pragma unroll
            for (int i = 0; i < 4; ++i) {
                int o = ot * 16 + quad * 4 + i;
                float S = acc[i] + cmat[o * 2112 + e];
                float sg = 1.0f / (1.0f + __expf(-S));
                zacc[ot][i] += sg * wv;
            }
        }
    }
    // reduce over the 16 e-lanes within each quad
    #pragma unroll
    for (int m = 1; m < 16; m <<= 1)
        #pragma unroll
        for (int ot = 0; ot < 4; ++ot)
            #pragma unroll
            for (int i = 0; i < 4; ++i)
                zacc[ot][i] += __shfl_xor(zacc[ot][i], m, 64);

    __shared__ float zp[4][64];
    if (l16 == 0) {
        #pragma unroll
        for (int ot = 0; ot < 4; ++ot)
            #pragma unroll
            for (int i = 0; i < 4; ++i)
                zp[w][ot * 16 + quad * 4 + i] = zacc[ot][i];
    }
    __syncthreads();
    if (t < 64) {
        float z = zp[0][t] + zp[1][t] + zp[2][t] + zp[3][t] + outB[0];
        float pa = preluA[0];
        out[b * 64 + t] = (z >= 0.0f) ? z : pa * z;
    }
}

extern "C" void kernel_launch(void* const* d_in, const int* in_sizes, int n_in,
                              void* d_out, int out_size, void* d_ws, size_t ws_size,
                              hipStream_t stream)
{
    const float* x       = (const float*)d_in[0];
    const float* fc_in_W = (const float*)d_in[1];
    const float* fc_in_b = (const float*)d_in[2];
    const float* fc1_W   = (const float*)d_in[3];
    const float* fc1_b   = (const float*)d_in[4];
    const float* out1_W  = (const float*)d_in[5];
    const float* out1_b  = (const float*)d_in[6];
    const float* cW      = (const float*)d_in[7];
    const float* cB      = (const float*)d_in[8];
    const float* cattW   = (const float*)d_in[9];
    const float* oattW   = (const float*)d_in[10];
    const float* ntW     = (const float*)d_in[11];
    const float* tgw     = (const float*)d_in[12];
    const float* outW    = (const float*)d_in[13];
    const float* outB    = (const float*)d_in[14];
    const float* preluA  = (const float*)d_in[15];
    const float* coef_m  = (const float*)d_in[16];
    float* out = (float*)d_out;
    float* ws  = (float*)d_ws;

    // workspace layout (float offsets)
    float* h1p  = ws;                    // 4*524288   = 2097152
    float* h1   = ws + 2097152;          // 524288
    float* h2p  = ws + 2621440;          // 8*65536    = 524288
    float* h2   = ws + 3145728;          // 65536
    float* h3   = ws + 3211264;          // 2097152
    float* cfs  = ws + 5308416;          // 131072
    float* att  = ws + 5439488;          // 131072
    float* natt = ws + 5570560;          // 131072
    float* cp   = ws + 5701632;          // 4*135168   = 540672
    float* cmat = ws + 6242304;          // 135168
    unsigned short* nt1b = (unsigned short*)(ws + 6377472);  // 2097152 ushorts
    unsigned short* Gb   = (unsigned short*)(ws + 7426048);  // 135168 ushorts
    // total 7,493,632 floats (~30.0 MB)

    // trunk MLP
    gemm_bt<<<dim3(16, 8, 4), 256, 0, stream>>>(x, 2000, fc_in_W, 2000,
                                                h1p, 1024, 524288L, 2000, 500);
    reduce_partials<<<2048, 256, 0, stream>>>(h1p, h1, 524288, 4, 524288L,
                                              fc_in_b, 1024, 1);
    gemm_bt<<<dim3(2, 8, 8), 256, 0, stream>>>(h1, 1024, fc1_W, 1024,
                                               h2p, 128, 65536L, 1024, 128);
    reduce_partials<<<256, 256, 0, stream>>>(h2p, h2, 65536, 8, 65536L,
                                             fc1_b, 128, 1);
    gemm_bt<<<dim3(64, 8, 1), 256, 0, stream>>>(h2, 128, out1_W, 128,
                                                h3, 4096, 0L, 128, 128);

    // batch-independent attention-coefficient path
    coef_kernel<<<4096, 64, 0, stream>>>(coef_m, cW, cB, cattW, cfs);
    att_kernel<<<64, 256, 0, stream>>>(cfs, oattW, att);
    natt_kernel<<<64, 256, 0, stream>>>(ntW, att, natt);
    gemm_bt<<<dim3(33, 1, 4), 256, 0, stream>>>(natt, 2048, tgw + 64, 2112,
                                                cp, 2112, 135168L, 2048, 512);
    reduce_partials<<<528, 256, 0, stream>>>(cp, cmat, 135168, 4, 135168L,
                                             nullptr, 1, 0);

    // bf16 conversions + batch-dependent path
    conv_g<<<528, 256, 0, stream>>>(tgw, Gb);
    nt1_kernel<<<512, 256, 0, stream>>>(h3, out1_b, ntW, nt1b);
    final_mfma<<<512, 256, 0, stream>>>(nt1b, Gb, cmat, outW, outB, preluA, out);
}

// Round 3
// 345.450 us; speedup vs baseline: 1.8614x; 1.3092x over previous
//
#include <hip/hip_runtime.h>
#include <math.h>

typedef __attribute__((ext_vector_type(8))) short bf16x8;
typedef __attribute__((ext_vector_type(4))) float f32x4;

static __device__ __forceinline__ float eluf(float x) {
    return x > 0.0f ? x : expm1f(x);
}

static __device__ __forceinline__ unsigned short f2bf(float f) {
    unsigned int u = __float_as_uint(f);
    unsigned int r = (u + 0x7FFFu + ((u >> 16) & 1u)) >> 16;
    return (unsigned short)r;
}

// ---------------------------------------------------------------------------
// Conversions f32 -> bf16
// ---------------------------------------------------------------------------
__global__ __launch_bounds__(256) void conv_bf16(
    const float* __restrict__ src, unsigned short* __restrict__ dst,
    int rows, int sld, int dld)
{
    int idx = blockIdx.x * 256 + threadIdx.x;
    if (idx >= rows * dld) return;
    int r = idx / dld, k = idx - r * dld;
    dst[idx] = (k < sld) ? f2bf(src[(size_t)r * sld + k]) : (unsigned short)0;
}

// out1_W rows permuted: dst row n' = d*64+p <- src row p*64+d  (K=128)
__global__ __launch_bounds__(256) void conv_permW(
    const float* __restrict__ src, unsigned short* __restrict__ dst)
{
    int idx = blockIdx.x * 256 + threadIdx.x;
    if (idx >= 4096 * 128) return;
    int n = idx >> 7, k = idx & 127;
    int d = n >> 6, p = n & 63;
    dst[idx] = f2bf(src[(size_t)((p << 6) | d) * 128 + k]);
}

// split tgw: cols 0..63 -> Gb [2112,64], cols 64.. -> G2b [2112,2048]
__global__ __launch_bounds__(256) void conv_tgw(
    const float* __restrict__ tgw, unsigned short* __restrict__ Gb,
    unsigned short* __restrict__ G2b)
{
    int idx = blockIdx.x * 256 + threadIdx.x;
    if (idx >= 2112 * 2112) return;
    int e = idx / 2112, k = idx - e * 2112;
    unsigned short v = f2bf(tgw[idx]);
    if (k < 64) Gb[e * 64 + k] = v;
    else        G2b[(size_t)e * 2048 + (k - 64)] = v;
}

// ---------------------------------------------------------------------------
// Generic bf16 MFMA GEMM-BT: C[m,n] = sum_k A[m,k]*B[n,k]. 64x64 tiles.
// grid (N/64, M/64, z), block 256. K covered = z*kchunk (mult of 32).
// mode 0: f32 partial store to C + bz*strideCz
// mode 1: bf16 relu(acc+bias[n]) -> Cb ;  mode 2: same, bias index permuted
// ---------------------------------------------------------------------------
__global__ __launch_bounds__(256) void gemm_mfma(
    const unsigned short* __restrict__ A, int lda,
    const unsigned short* __restrict__ B, int ldb,
    float* __restrict__ C, unsigned short* __restrict__ Cb,
    int ldc, long strideCz,
    const float* __restrict__ bias, int mode, int kchunk)
{
    __shared__ __align__(16) unsigned short As[64 * 40];
    __shared__ __align__(16) unsigned short Bs[64 * 40];
    const int t = threadIdx.x;
    const int w = t >> 6, lane = t & 63, l16 = lane & 15, quad = lane >> 4;
    const int n0 = blockIdx.x * 64, m0 = blockIdx.y * 64;
    const int kb0 = blockIdx.z * kchunk;
    const int r = t >> 2, koff = (t & 3) * 8;
    if (mode == 0) C += (size_t)blockIdx.z * strideCz;

    f32x4 acc[4] = {};
    for (int kb = kb0; kb < kb0 + kchunk; kb += 32) {
        bf16x8 av = *reinterpret_cast<const bf16x8*>(&A[(size_t)(m0 + r) * lda + kb + koff]);
        bf16x8 bv = *reinterpret_cast<const bf16x8*>(&B[(size_t)(n0 + r) * ldb + kb + koff]);
        __syncthreads();
        *reinterpret_cast<bf16x8*>(&As[r * 40 + koff]) = av;
        *reinterpret_cast<bf16x8*>(&Bs[r * 40 + koff]) = bv;
        __syncthreads();
        bf16x8 af = *reinterpret_cast<const bf16x8*>(&As[(w * 16 + l16) * 40 + quad * 8]);
        #pragma unroll
        for (int nt = 0; nt < 4; ++nt) {
            bf16x8 bf = *reinterpret_cast<const bf16x8*>(&Bs[(nt * 16 + l16) * 40 + quad * 8]);
            acc[nt] = __builtin_amdgcn_mfma_f32_16x16x32_bf16(af, bf, acc[nt], 0, 0, 0);
        }
    }
    #pragma unroll
    for (int nt = 0; nt < 4; ++nt)
        #pragma unroll
        for (int i = 0; i < 4; ++i) {
            int m = m0 + w * 16 + quad * 4 + i;
            int n = n0 + nt * 16 + l16;
            if (mode == 0) {
                C[(size_t)m * ldc + n] = acc[nt][i];
            } else {
                int bidx = (mode == 2) ? (((n & 63) << 6) | (n >> 6)) : n;
                float v = acc[nt][i] + bias[bidx];
                v = fmaxf(v, 0.0f);
                Cb[(size_t)m * ldc + n] = f2bf(v);
            }
        }
}

// dst = act( sum_j src[i + j*pstride] + bias[i & biasMask] ); f32 or bf16 out
__global__ __launch_bounds__(256) void reduce_partials(
    const float* __restrict__ src, float* __restrict__ dstF,
    unsigned short* __restrict__ dstB, int n,
    int nparts, long pstride, const float* __restrict__ bias, int biasMask, int doRelu)
{
    int i = blockIdx.x * 256 + threadIdx.x;
    if (i >= n) return;
    float a = 0.0f;
    for (int j = 0; j < nparts; ++j) a += src[i + (long)j * pstride];
    if (bias) a += bias[i & biasMask];
    if (doRelu) a = fmaxf(a, 0.0f);
    if (dstB) dstB[i] = f2bf(a); else dstF[i] = a;
}

// ---------------------------------------------------------------------------
// Coef pipeline part 1: per (x,y) pair -> cfs[x,y,0:32]
// ---------------------------------------------------------------------------
__global__ __launch_bounds__(64) void coef_kernel(
    const float* __restrict__ coef_m,   // [64,64,8]
    const float* __restrict__ cW,       // [8,32]
    const float* __restrict__ cB,       // [8,32]
    const float* __restrict__ attW,     // [8,32,32]
    float* __restrict__ cfs)            // [64,64,32]
{
    __shared__ float cf_s[256];
    __shared__ float part[64];
    const int t  = threadIdx.x;
    const int xy = blockIdx.x;
    float ls = 0.0f;
    #pragma unroll
    for (int i = 0; i < 4; ++i) {
        int idx = i * 64 + t;
        int f = idx >> 5;
        float v = eluf(coef_m[xy * 8 + f] * cW[idx] + cB[idx]);
        cf_s[idx] = v;
        ls += expf(eluf(v));
    }
    #pragma unroll
    for (int m = 1; m < 64; m <<= 1) ls += __shfl_xor(ls, m, 64);
    __syncthreads();
    const float s = ls;
    const int g = t & 31, fg = t >> 5;
    float acc = 0.0f;
    for (int f = fg * 4; f < fg * 4 + 4; ++f) {
        float lin = 0.0f;
        for (int h = 0; h < 32; ++h)
            lin += cf_s[f * 32 + h] * attW[f * 1024 + g * 32 + h];
        float e = expf(eluf(cf_s[f * 32 + g]));
        acc += eluf(e * lin / s);
    }
    part[t] = acc;
    __syncthreads();
    if (t < 32) {
        float tot = part[t] + part[t + 32];
        cfs[xy * 32 + t] = eluf(tot * 0.125f);
    }
}

// ---------------------------------------------------------------------------
// Coef pipeline part 2: node attention -> att[o, i*32+g]
// ---------------------------------------------------------------------------
__global__ __launch_bounds__(256) void att_kernel(
    const float* __restrict__ cfs,     // [64,64,32]
    const float* __restrict__ oattW,   // [64,32,32]
    float* __restrict__ att)           // [64,2048]
{
    __shared__ float L[2048];
    __shared__ float red[256];
    __shared__ float csum[32];
    const int t = threadIdx.x;
    const int o = blockIdx.x;
    #pragma unroll
    for (int j = 0; j < 8; ++j) L[t + 256 * j] = cfs[o * 2048 + t + 256 * j];
    __syncthreads();
    {
        int h = t & 31, ig = t >> 5;
        float ps = 0.0f;
        for (int i = ig * 8; i < ig * 8 + 8; ++i) ps += expf(eluf(L[i * 32 + h]));
        red[t] = ps;
        __syncthreads();
        if (t < 32) {
            float cs = 0.0f;
            #pragma unroll
            for (int j = 0; j < 8; ++j) cs += red[t + 32 * j];
            csum[t] = cs;
        }
        __syncthreads();
    }
    #pragma unroll
    for (int j = 0; j < 8; ++j) {
        int idx = t + 256 * j;
        int i = idx >> 5, g = idx & 31;
        float lin2 = 0.0f;
        for (int h = 0; h < 32; ++h)
            lin2 += L[i * 32 + h] * oattW[i * 1024 + g * 32 + h];
        float p2 = expf(eluf(L[idx])) / csum[g];
        att[o * 2048 + idx] = p2 * lin2;
    }
}

// ---------------------------------------------------------------------------
// nattb[o,d] = bf16( sum_p ntW[o,p] * att[p,d] )  grid 128 (d-tiles of 16)
// ---------------------------------------------------------------------------
__global__ __launch_bounds__(256) void natt_new(
    const float* __restrict__ ntW,   // [64,64]
    const float* __restrict__ att,   // [64,2048]
    unsigned short* __restrict__ nattb) // [64,2048] bf16
{
    __shared__ float ntW_s[64 * 65];
    __shared__ float att_s[64 * 17];
    const int t = threadIdx.x;
    const int d0 = blockIdx.x * 16;
    #pragma unroll
    for (int j = 0; j < 16; ++j) {
        int idx = t + 256 * j;
        ntW_s[(idx >> 6) * 65 + (idx & 63)] = ntW[idx];
    }
    #pragma unroll
    for (int j = 0; j < 4; ++j) {
        int idx = t + 256 * j;
        int p = idx >> 4, dd = idx & 15;
        att_s[p * 17 + dd] = att[p * 2048 + d0 + dd];
    }
    __syncthreads();
    const int dd = t & 15, ob = (t >> 4) * 4;
    float acc[4] = {0.0f, 0.0f, 0.0f, 0.0f};
    for (int p = 0; p < 64; ++p) {
        float av = att_s[p * 17 + dd];
        #pragma unroll
        for (int i = 0; i < 4; ++i) acc[i] += ntW_s[(ob + i) * 65 + p] * av;
    }
    #pragma unroll
    for (int i = 0; i < 4; ++i)
        nattb[(ob + i) * 2048 + d0 + dd] = f2bf(acc[i]);
}

// ---------------------------------------------------------------------------
// Final fused kernel: nt1 (MFMA, from hbT+ntWb) then
// z[b,o] = prelu( sum_e sigmoid( dot64(nt1, G[e]) + c[o,e] ) * w[e] + b )
// grid 512 (b), block 256 = 4 waves
// ---------------------------------------------------------------------------
__global__ __launch_bounds__(256) void final_mfma(
    const unsigned short* __restrict__ hbT,  // [512][4096] bf16, idx d*64+p
    const unsigned short* __restrict__ Wb,   // [64,64] bf16 (ntW)
    const unsigned short* __restrict__ Gb,   // [2112,64] bf16
    const float* __restrict__ cmat,   // [64,2112]
    const float* __restrict__ outW,   // [2112]
    const float* __restrict__ outB,   // [1]
    const float* __restrict__ preluA, // [1]
    float* __restrict__ out)          // [512,64]
{
    __shared__ __align__(16) unsigned short HtT[64 * 72];   // [d][p]
    __shared__ __align__(16) unsigned short nt1_s[64 * 72]; // [o][d]
    __shared__ float zp[4][64];
    const int t = threadIdx.x;
    const int w = t >> 6;
    const int lane = t & 63;
    const int l16 = lane & 15, quad = lane >> 4;
    const int b = blockIdx.x;

    // stage hbT row b -> LDS [d][p]
    const unsigned short* src = hbT + (size_t)b * 4096;
    #pragma unroll
    for (int j = 0; j < 2; ++j) {
        int c = t + j * 256;
        *reinterpret_cast<bf16x8*>(&HtT[(c >> 3) * 72 + (c & 7) * 8]) =
            *reinterpret_cast<const bf16x8*>(&src[c * 8]);
    }
    __syncthreads();

    // nt1 tiles: wave w owns o-rows [w*16,+16), all 4 d-tiles
    bf16x8 aW[2];
    #pragma unroll
    for (int h = 0; h < 2; ++h)
        aW[h] = *reinterpret_cast<const bf16x8*>(&Wb[(w * 16 + l16) * 64 + h * 32 + quad * 8]);
    #pragma unroll
    for (int dt = 0; dt < 4; ++dt) {
        f32x4 acc = {0.0f, 0.0f, 0.0f, 0.0f};
        #pragma unroll
        for (int h = 0; h < 2; ++h) {
            bf16x8 bf = *reinterpret_cast<const bf16x8*>(
                &HtT[(dt * 16 + l16) * 72 + h * 32 + quad * 8]);
            acc = __builtin_amdgcn_mfma_f32_16x16x32_bf16(aW[h], bf, acc, 0, 0, 0);
        }
        #pragma unroll
        for (int i = 0; i < 4; ++i)
            nt1_s[(w * 16 + quad * 4 + i) * 72 + dt * 16 + l16] = f2bf(acc[i]);
    }
    __syncthreads();

    // A-fragments of nt1 for the e-loop
    bf16x8 afr[4][2];
    #pragma unroll
    for (int ot = 0; ot < 4; ++ot)
        #pragma unroll
        for (int h = 0; h < 2; ++h)
            afr[ot][h] = *reinterpret_cast<const bf16x8*>(
                &nt1_s[(ot * 16 + l16) * 72 + h * 32 + quad * 8]);

    float zacc[4][4] = {};
    for (int ec = 0; ec < 33; ++ec) {
        const int e = ec * 64 + w * 16 + l16;
        bf16x8 bfr0 = *reinterpret_cast<const bf16x8*>(Gb + (size_t)e * 64 + quad * 8);
        bf16x8 bfr1 = *reinterpret_cast<const bf16x8*>(Gb + (size_t)e * 64 + 32 + quad * 8);
        const float wv = outW[e];
        #pragma unroll
        for (int ot = 0; ot < 4; ++ot) {
            f32x4 acc = {0.0f, 0.0f, 0.0f, 0.0f};
            acc = __builtin_amdgcn_mfma_f32_16x16x32_bf16(afr[ot][0], bfr0, acc, 0, 0, 0);
            acc = __builtin_amdgcn_mfma_f32_16x16x32_bf16(afr[ot][1], bfr1, acc, 0, 0, 0);
            #pragma unroll
            for (int i = 0; i < 4; ++i) {
                int o = ot * 16 + quad * 4 + i;
                float S = acc[i] + cmat[o * 2112 + e];
                float sg = 1.0f / (1.0f + __expf(-S));
                zacc[ot][i] += sg * wv;
            }
        }
    }
    #pragma unroll
    for (int m = 1; m < 16; m <<= 1)
        #pragma unroll
        for (int ot = 0; ot < 4; ++ot)
            #pragma unroll
            for (int i = 0; i < 4; ++i)
                zacc[ot][i] += __shfl_xor(zacc[ot][i], m, 64);

    if (l16 == 0) {
        #pragma unroll
        for (int ot = 0; ot < 4; ++ot)
            #pragma unroll
            for (int i = 0; i < 4; ++i)
                zp[w][ot * 16 + quad * 4 + i] = zacc[ot][i];
    }
    __syncthreads();
    if (t < 64) {
        float z = zp[0][t] + zp[1][t] + zp[2][t] + zp[3][t] + outB[0];
        float pa = preluA[0];
        out[b * 64 + t] = (z >= 0.0f) ? z : pa * z;
    }
}

extern "C" void kernel_launch(void* const* d_in, const int* in_sizes, int n_in,
                              void* d_out, int out_size, void* d_ws, size_t ws_size,
                              hipStream_t stream)
{
    const float* x       = (const float*)d_in[0];
    const float* fc_in_W = (const float*)d_in[1];
    const float* fc_in_b = (const float*)d_in[2];
    const float* fc1_W   = (const float*)d_in[3];
    const float* fc1_b   = (const float*)d_in[4];
    const float* out1_W  = (const float*)d_in[5];
    const float* out1_b  = (const float*)d_in[6];
    const float* cW      = (const float*)d_in[7];
    const float* cB      = (const float*)d_in[8];
    const float* cattW   = (const float*)d_in[9];
    const float* oattW   = (const float*)d_in[10];
    const float* ntW     = (const float*)d_in[11];
    const float* tgw     = (const float*)d_in[12];
    const float* outW    = (const float*)d_in[13];
    const float* outB    = (const float*)d_in[14];
    const float* preluA  = (const float*)d_in[15];
    const float* coef_m  = (const float*)d_in[16];
    float* out = (float*)d_out;
    float* ws  = (float*)d_ws;

    // workspace layout (float offsets); regions reused stream-ordered
    unsigned short* xb      = (unsigned short*)(ws + 0);          // 524,288 us
    unsigned short* fcinWb  = (unsigned short*)(ws + 524288);     // 2,097,152 us
    float*          cp      = ws + 0;                             // reuses xb/fcinWb
    float*          h1p     = ws + 1572864;                       // 2,097,152 f
    unsigned short* hbT     = (unsigned short*)(ws + 1572864);    // reuses h1p
    unsigned short* h1b     = (unsigned short*)(ws + 3670016);    // 524,288 us
    unsigned short* fc1Wb   = (unsigned short*)(ws + 3932160);    // 131,072 us
    float*          h2p     = ws + 3997696;                       // 262,144 f
    unsigned short* h2b     = (unsigned short*)(ws + 4259840);    // 65,536 us
    unsigned short* out1WbT = (unsigned short*)(ws + 4292608);    // 524,288 us
    unsigned short* Wb      = (unsigned short*)(ws + 4554752);    // 4,096 us
    unsigned short* Gb      = (unsigned short*)(ws + 4556800);    // 135,168 us
    unsigned short* G2b     = (unsigned short*)(ws + 4624384);    // 4,325,376 us
    float*          cfs     = ws + 6787072;                       // 131,072 f
    float*          att     = ws + 6918144;                       // 131,072 f
    unsigned short* nattb   = (unsigned short*)(ws + 7049216);    // 131,072 us
    float*          cmat    = ws + 7114752;                       // 135,168 f
    // total 7,249,920 floats (~29.0 MB)

    // conversions
    conv_bf16<<<4096, 256, 0, stream>>>(x, xb, 512, 2000, 2048);
    conv_bf16<<<8192, 256, 0, stream>>>(fc_in_W, fcinWb, 1024, 2000, 2048);
    conv_bf16<<<512, 256, 0, stream>>>(fc1_W, fc1Wb, 128, 1024, 1024);
    conv_bf16<<<16, 256, 0, stream>>>(ntW, Wb, 64, 64, 64);
    conv_permW<<<2048, 256, 0, stream>>>(out1_W, out1WbT);
    conv_tgw<<<17424, 256, 0, stream>>>(tgw, Gb, G2b);

    // batch-independent attention-coefficient path
    coef_kernel<<<4096, 64, 0, stream>>>(coef_m, cW, cB, cattW, cfs);
    att_kernel<<<64, 256, 0, stream>>>(cfs, oattW, att);
    natt_new<<<128, 256, 0, stream>>>(ntW, att, nattb);

    // trunk MLP (bf16 MFMA)
    gemm_mfma<<<dim3(16, 8, 4), 256, 0, stream>>>(xb, 2048, fcinWb, 2048,
        h1p, nullptr, 1024, 524288L, nullptr, 0, 512);
    reduce_partials<<<2048, 256, 0, stream>>>(h1p, nullptr, h1b, 524288, 4,
        524288L, fc_in_b, 1023, 1);
    gemm_mfma<<<dim3(2, 8, 4), 256, 0, stream>>>(h1b, 1024, fc1Wb, 1024,
        h2p, nullptr, 128, 65536L, nullptr, 0, 256);
    reduce_partials<<<256, 256, 0, stream>>>(h2p, nullptr, h2b, 65536, 4,
        65536L, fc1_b, 127, 1);
    // out1: emits hbT = bf16 relu(h3+b) transposed per b (weights pre-permuted)
    gemm_mfma<<<dim3(64, 8, 1), 256, 0, stream>>>(h2b, 128, out1WbT, 128,
        nullptr, hbT, 4096, 0L, out1_b, 2, 128);

    // cmat[o,e] = sum_d natt[o,d]*tgw[e,64+d]   (bf16 MFMA, k-split 8)
    gemm_mfma<<<dim3(33, 1, 8), 256, 0, stream>>>(nattb, 2048, G2b, 2048,
        cp, nullptr, 2112, 135168L, nullptr, 0, 256);
    reduce_partials<<<528, 256, 0, stream>>>(cp, cmat, nullptr, 135168, 8,
        135168L, nullptr, 0, 0);

    // fused nt1 + final
    final_mfma<<<512, 256, 0, stream>>>(hbT, Wb, Gb, cmat, outW, outB, preluA, out);
}

// Round 4
// 258.350 us; speedup vs baseline: 2.4890x; 1.3371x over previous
//
#include <hip/hip_runtime.h>
#include <math.h>

typedef __attribute__((ext_vector_type(8))) short bf16x8;
typedef __attribute__((ext_vector_type(4))) float f32x4;

static __device__ __forceinline__ float eluf(float x) {
    return x > 0.0f ? x : expm1f(x);
}

static __device__ __forceinline__ unsigned short f2bf(float f) {
    unsigned int u = __float_as_uint(f);
    unsigned int r = (u + 0x7FFFu + ((u >> 16) & 1u)) >> 16;
    return (unsigned short)r;
}

// ---------------------------------------------------------------------------
// Conversions f32 -> bf16
// ---------------------------------------------------------------------------
__global__ __launch_bounds__(256) void conv_bf16(
    const float* __restrict__ src, unsigned short* __restrict__ dst,
    int rows, int sld, int dld)
{
    int idx = blockIdx.x * 256 + threadIdx.x;
    if (idx >= rows * dld) return;
    int r = idx / dld, k = idx - r * dld;
    dst[idx] = (k < sld) ? f2bf(src[(size_t)r * sld + k]) : (unsigned short)0;
}

// out1_W rows permuted: dst row n' = d*64+p <- src row p*64+d  (K=128)
__global__ __launch_bounds__(256) void conv_permW(
    const float* __restrict__ src, unsigned short* __restrict__ dst)
{
    int idx = blockIdx.x * 256 + threadIdx.x;
    if (idx >= 4096 * 128) return;
    int n = idx >> 7, k = idx & 127;
    int d = n >> 6, p = n & 63;
    dst[idx] = f2bf(src[(size_t)((p << 6) | d) * 128 + k]);
}

// split tgw: cols 0..63 -> Gb [2112,64], cols 64.. -> G2b [2112,2048]
__global__ __launch_bounds__(256) void conv_tgw(
    const float* __restrict__ tgw, unsigned short* __restrict__ Gb,
    unsigned short* __restrict__ G2b)
{
    int idx = blockIdx.x * 256 + threadIdx.x;
    if (idx >= 2112 * 2112) return;
    int e = idx / 2112, k = idx - e * 2112;
    unsigned short v = f2bf(tgw[idx]);
    if (k < 64) Gb[e * 64 + k] = v;
    else        G2b[(size_t)e * 2048 + (k - 64)] = v;
}

// ---------------------------------------------------------------------------
// Generic bf16 MFMA GEMM-BT: C[m,n] = sum_k A[m,k]*B[n,k]. 64x64 tiles.
// grid (N/64, M/64, z), block 256. K covered = z*kchunk (mult of 32).
// mode 0: f32 partial store to C + bz*strideCz
// mode 1: bf16 relu(acc+bias[n]) -> Cb ;  mode 2: same, bias index permuted
// ---------------------------------------------------------------------------
__global__ __launch_bounds__(256) void gemm_mfma(
    const unsigned short* __restrict__ A, int lda,
    const unsigned short* __restrict__ B, int ldb,
    float* __restrict__ C, unsigned short* __restrict__ Cb,
    int ldc, long strideCz,
    const float* __restrict__ bias, int mode, int kchunk)
{
    __shared__ __align__(16) unsigned short As[64 * 40];
    __shared__ __align__(16) unsigned short Bs[64 * 40];
    const int t = threadIdx.x;
    const int w = t >> 6, lane = t & 63, l16 = lane & 15, quad = lane >> 4;
    const int n0 = blockIdx.x * 64, m0 = blockIdx.y * 64;
    const int kb0 = blockIdx.z * kchunk;
    const int r = t >> 2, koff = (t & 3) * 8;
    if (mode == 0) C += (size_t)blockIdx.z * strideCz;

    f32x4 acc[4] = {};
    for (int kb = kb0; kb < kb0 + kchunk; kb += 32) {
        bf16x8 av = *reinterpret_cast<const bf16x8*>(&A[(size_t)(m0 + r) * lda + kb + koff]);
        bf16x8 bv = *reinterpret_cast<const bf16x8*>(&B[(size_t)(n0 + r) * ldb + kb + koff]);
        __syncthreads();
        *reinterpret_cast<bf16x8*>(&As[r * 40 + koff]) = av;
        *reinterpret_cast<bf16x8*>(&Bs[r * 40 + koff]) = bv;
        __syncthreads();
        bf16x8 af = *reinterpret_cast<const bf16x8*>(&As[(w * 16 + l16) * 40 + quad * 8]);
        #pragma unroll
        for (int nt = 0; nt < 4; ++nt) {
            bf16x8 bf = *reinterpret_cast<const bf16x8*>(&Bs[(nt * 16 + l16) * 40 + quad * 8]);
            acc[nt] = __builtin_amdgcn_mfma_f32_16x16x32_bf16(af, bf, acc[nt], 0, 0, 0);
        }
    }
    #pragma unroll
    for (int nt = 0; nt < 4; ++nt)
        #pragma unroll
        for (int i = 0; i < 4; ++i) {
            int m = m0 + w * 16 + quad * 4 + i;
            int n = n0 + nt * 16 + l16;
            if (mode == 0) {
                C[(size_t)m * ldc + n] = acc[nt][i];
            } else {
                int bidx = (mode == 2) ? (((n & 63) << 6) | (n >> 6)) : n;
                float v = acc[nt][i] + bias[bidx];
                v = fmaxf(v, 0.0f);
                Cb[(size_t)m * ldc + n] = f2bf(v);
            }
        }
}

// dst = act( sum_j src[i + j*pstride] + bias[i & biasMask] ); f32 or bf16 out
__global__ __launch_bounds__(256) void reduce_partials(
    const float* __restrict__ src, float* __restrict__ dstF,
    unsigned short* __restrict__ dstB, int n,
    int nparts, long pstride, const float* __restrict__ bias, int biasMask, int doRelu)
{
    int i = blockIdx.x * 256 + threadIdx.x;
    if (i >= n) return;
    float a = 0.0f;
    for (int j = 0; j < nparts; ++j) a += src[i + (long)j * pstride];
    if (bias) a += bias[i & biasMask];
    if (doRelu) a = fmaxf(a, 0.0f);
    if (dstB) dstB[i] = f2bf(a); else dstF[i] = a;
}

// ---------------------------------------------------------------------------
// Coef pipeline part 1: per (x,y) pair -> cfs[x,y,0:32]
// ---------------------------------------------------------------------------
__global__ __launch_bounds__(64) void coef_kernel(
    const float* __restrict__ coef_m,   // [64,64,8]
    const float* __restrict__ cW,       // [8,32]
    const float* __restrict__ cB,       // [8,32]
    const float* __restrict__ attW,     // [8,32,32]
    float* __restrict__ cfs)            // [64,64,32]
{
    __shared__ float cf_s[256];
    __shared__ float part[64];
    const int t  = threadIdx.x;
    const int xy = blockIdx.x;
    float ls = 0.0f;
    #pragma unroll
    for (int i = 0; i < 4; ++i) {
        int idx = i * 64 + t;
        int f = idx >> 5;
        float v = eluf(coef_m[xy * 8 + f] * cW[idx] + cB[idx]);
        cf_s[idx] = v;
        ls += expf(eluf(v));
    }
    #pragma unroll
    for (int m = 1; m < 64; m <<= 1) ls += __shfl_xor(ls, m, 64);
    __syncthreads();
    const float s = ls;
    const int g = t & 31, fg = t >> 5;
    float acc = 0.0f;
    for (int f = fg * 4; f < fg * 4 + 4; ++f) {
        float lin = 0.0f;
        for (int h = 0; h < 32; ++h)
            lin += cf_s[f * 32 + h] * attW[f * 1024 + g * 32 + h];
        float e = expf(eluf(cf_s[f * 32 + g]));
        acc += eluf(e * lin / s);
    }
    part[t] = acc;
    __syncthreads();
    if (t < 32) {
        float tot = part[t] + part[t + 32];
        cfs[xy * 32 + t] = eluf(tot * 0.125f);
    }
}

// ---------------------------------------------------------------------------
// Coef pipeline part 2: node attention -> att[o, i*32+g]
// ---------------------------------------------------------------------------
__global__ __launch_bounds__(256) void att_kernel(
    const float* __restrict__ cfs,     // [64,64,32]
    const float* __restrict__ oattW,   // [64,32,32]
    float* __restrict__ att)           // [64,2048]
{
    __shared__ float L[2048];
    __shared__ float red[256];
    __shared__ float csum[32];
    const int t = threadIdx.x;
    const int o = blockIdx.x;
    #pragma unroll
    for (int j = 0; j < 8; ++j) L[t + 256 * j] = cfs[o * 2048 + t + 256 * j];
    __syncthreads();
    {
        int h = t & 31, ig = t >> 5;
        float ps = 0.0f;
        for (int i = ig * 8; i < ig * 8 + 8; ++i) ps += expf(eluf(L[i * 32 + h]));
        red[t] = ps;
        __syncthreads();
        if (t < 32) {
            float cs = 0.0f;
            #pragma unroll
            for (int j = 0; j < 8; ++j) cs += red[t + 32 * j];
            csum[t] = cs;
        }
        __syncthreads();
    }
    #pragma unroll
    for (int j = 0; j < 8; ++j) {
        int idx = t + 256 * j;
        int i = idx >> 5, g = idx & 31;
        float lin2 = 0.0f;
        for (int h = 0; h < 32; ++h)
            lin2 += L[i * 32 + h] * oattW[i * 1024 + g * 32 + h];
        float p2 = expf(eluf(L[idx])) / csum[g];
        att[o * 2048 + idx] = p2 * lin2;
    }
}

// ---------------------------------------------------------------------------
// nattb[o,d] = bf16( sum_p ntW[o,p] * att[p,d] )  grid 128 (d-tiles of 16)
// ---------------------------------------------------------------------------
__global__ __launch_bounds__(256) void natt_new(
    const float* __restrict__ ntW,   // [64,64]
    const float* __restrict__ att,   // [64,2048]
    unsigned short* __restrict__ nattb) // [64,2048] bf16
{
    __shared__ float ntW_s[64 * 65];
    __shared__ float att_s[64 * 17];
    const int t = threadIdx.x;
    const int d0 = blockIdx.x * 16;
    #pragma unroll
    for (int j = 0; j < 16; ++j) {
        int idx = t + 256 * j;
        ntW_s[(idx >> 6) * 65 + (idx & 63)] = ntW[idx];
    }
    #pragma unroll
    for (int j = 0; j < 4; ++j) {
        int idx = t + 256 * j;
        int p = idx >> 4, dd = idx & 15;
        att_s[p * 17 + dd] = att[p * 2048 + d0 + dd];
    }
    __syncthreads();
    const int dd = t & 15, ob = (t >> 4) * 4;
    float acc[4] = {0.0f, 0.0f, 0.0f, 0.0f};
    for (int p = 0; p < 64; ++p) {
        float av = att_s[p * 17 + dd];
        #pragma unroll
        for (int i = 0; i < 4; ++i) acc[i] += ntW_s[(ob + i) * 65 + p] * av;
    }
    #pragma unroll
    for (int i = 0; i < 4; ++i)
        nattb[(ob + i) * 2048 + d0 + dd] = f2bf(acc[i]);
}

// ---------------------------------------------------------------------------
// Final fused kernel (e-split partials): nt1 (MFMA from hbT+Wb), then for
// ec in {z, z+4, ...}: S = nt1·G^T + cmatT ; zpart[z,b,o] = sum sigmoid(S)*w[e]
// grid (512, 4), block 256 = 4 waves
// ---------------------------------------------------------------------------
__global__ __launch_bounds__(256) void final_part(
    const unsigned short* __restrict__ hbT,  // [512][4096] bf16, idx d*64+p
    const unsigned short* __restrict__ Wb,   // [64,64] bf16 (ntW)
    const unsigned short* __restrict__ Gb,   // [2112,64] bf16
    const float* __restrict__ cmatT,  // [2112,64]
    const float* __restrict__ outW,   // [2112]
    float* __restrict__ zpart)        // [4][512][64]
{
    __shared__ __align__(16) unsigned short HtT[64 * 72];   // [d][p]
    __shared__ __align__(16) unsigned short nt1_s[64 * 72]; // [o][d]
    __shared__ float zp[4][64];
    const int t = threadIdx.x;
    const int w = t >> 6;
    const int lane = t & 63;
    const int l16 = lane & 15, quad = lane >> 4;
    const int b = blockIdx.x;
    const int z = blockIdx.y;

    // stage hbT row b -> LDS [d][p]
    const unsigned short* src = hbT + (size_t)b * 4096;
    #pragma unroll
    for (int j = 0; j < 2; ++j) {
        int c = t + j * 256;
        *reinterpret_cast<bf16x8*>(&HtT[(c >> 3) * 72 + (c & 7) * 8]) =
            *reinterpret_cast<const bf16x8*>(&src[c * 8]);
    }
    __syncthreads();

    // nt1 tiles: wave w owns o-rows [w*16,+16), all 4 d-tiles
    bf16x8 aW[2];
    #pragma unroll
    for (int h = 0; h < 2; ++h)
        aW[h] = *reinterpret_cast<const bf16x8*>(&Wb[(w * 16 + l16) * 64 + h * 32 + quad * 8]);
    #pragma unroll
    for (int dt = 0; dt < 4; ++dt) {
        f32x4 acc = {0.0f, 0.0f, 0.0f, 0.0f};
        #pragma unroll
        for (int h = 0; h < 2; ++h) {
            bf16x8 bf = *reinterpret_cast<const bf16x8*>(
                &HtT[(dt * 16 + l16) * 72 + h * 32 + quad * 8]);
            acc = __builtin_amdgcn_mfma_f32_16x16x32_bf16(aW[h], bf, acc, 0, 0, 0);
        }
        #pragma unroll
        for (int i = 0; i < 4; ++i)
            nt1_s[(w * 16 + quad * 4 + i) * 72 + dt * 16 + l16] = f2bf(acc[i]);
    }
    __syncthreads();

    // A-fragments of nt1 for the e-loop
    bf16x8 afr[4][2];
    #pragma unroll
    for (int ot = 0; ot < 4; ++ot)
        #pragma unroll
        for (int h = 0; h < 2; ++h)
            afr[ot][h] = *reinterpret_cast<const bf16x8*>(
                &nt1_s[(ot * 16 + l16) * 72 + h * 32 + quad * 8]);

    float zacc[4][4] = {};
    for (int ec = z; ec < 33; ec += 4) {
        const int e = ec * 64 + w * 16 + l16;
        bf16x8 bfr0 = *reinterpret_cast<const bf16x8*>(Gb + (size_t)e * 64 + quad * 8);
        bf16x8 bfr1 = *reinterpret_cast<const bf16x8*>(Gb + (size_t)e * 64 + 32 + quad * 8);
        const float wv = outW[e];
        #pragma unroll
        for (int ot = 0; ot < 4; ++ot) {
            f32x4 acc = {0.0f, 0.0f, 0.0f, 0.0f};
            acc = __builtin_amdgcn_mfma_f32_16x16x32_bf16(afr[ot][0], bfr0, acc, 0, 0, 0);
            acc = __builtin_amdgcn_mfma_f32_16x16x32_bf16(afr[ot][1], bfr1, acc, 0, 0, 0);
            float4 c4 = *reinterpret_cast<const float4*>(
                &cmatT[(size_t)e * 64 + ot * 16 + quad * 4]);
            float cc[4] = {c4.x, c4.y, c4.z, c4.w};
            #pragma unroll
            for (int i = 0; i < 4; ++i) {
                float S = acc[i] + cc[i];
                float sg = __builtin_amdgcn_rcpf(1.0f + __expf(-S));
                zacc[ot][i] += sg * wv;
            }
        }
    }
    #pragma unroll
    for (int m = 1; m < 16; m <<= 1)
        #pragma unroll
        for (int ot = 0; ot < 4; ++ot)
            #pragma unroll
            for (int i = 0; i < 4; ++i)
                zacc[ot][i] += __shfl_xor(zacc[ot][i], m, 64);

    if (l16 == 0) {
        #pragma unroll
        for (int ot = 0; ot < 4; ++ot)
            #pragma unroll
            for (int i = 0; i < 4; ++i)
                zp[w][ot * 16 + quad * 4 + i] = zacc[ot][i];
    }
    __syncthreads();
    if (t < 64)
        zpart[((size_t)z * 512 + b) * 64 + t] = zp[0][t] + zp[1][t] + zp[2][t] + zp[3][t];
}

// out[i] = prelu( sum_z zpart[z][i] + outB )
__global__ __launch_bounds__(256) void finish_kernel(
    const float* __restrict__ zpart, const float* __restrict__ outB,
    const float* __restrict__ preluA, float* __restrict__ out)
{
    int i = blockIdx.x * 256 + threadIdx.x;  // < 32768
    float z = zpart[i] + zpart[32768 + i] + zpart[65536 + i] + zpart[98304 + i] + outB[0];
    float pa = preluA[0];
    out[i] = (z >= 0.0f) ? z : pa * z;
}

extern "C" void kernel_launch(void* const* d_in, const int* in_sizes, int n_in,
                              void* d_out, int out_size, void* d_ws, size_t ws_size,
                              hipStream_t stream)
{
    const float* x       = (const float*)d_in[0];
    const float* fc_in_W = (const float*)d_in[1];
    const float* fc_in_b = (const float*)d_in[2];
    const float* fc1_W   = (const float*)d_in[3];
    const float* fc1_b   = (const float*)d_in[4];
    const float* out1_W  = (const float*)d_in[5];
    const float* out1_b  = (const float*)d_in[6];
    const float* cW      = (const float*)d_in[7];
    const float* cB      = (const float*)d_in[8];
    const float* cattW   = (const float*)d_in[9];
    const float* oattW   = (const float*)d_in[10];
    const float* ntW     = (const float*)d_in[11];
    const float* tgw     = (const float*)d_in[12];
    const float* outW    = (const float*)d_in[13];
    const float* outB    = (const float*)d_in[14];
    const float* preluA  = (const float*)d_in[15];
    const float* coef_m  = (const float*)d_in[16];
    float* out = (float*)d_out;
    float* ws  = (float*)d_ws;

    // workspace layout (float offsets); regions reused stream-ordered
    unsigned short* xb      = (unsigned short*)(ws + 0);          // 524,288 us
    unsigned short* fcinWb  = (unsigned short*)(ws + 524288);     // 2,097,152 us
    float*          cpT     = ws + 0;                             // reuses xb/fcinWb
    float*          h1p     = ws + 1572864;                       // 2,097,152 f
    unsigned short* hbT     = (unsigned short*)(ws + 1572864);    // reuses h1p
    unsigned short* h1b     = (unsigned short*)(ws + 3670016);    // 524,288 us
    unsigned short* fc1Wb   = (unsigned short*)(ws + 3932160);    // 131,072 us
    float*          h2p     = ws + 3997696;                       // 262,144 f
    unsigned short* h2b     = (unsigned short*)(ws + 4259840);    // 65,536 us
    unsigned short* out1WbT = (unsigned short*)(ws + 4292608);    // 524,288 us
    unsigned short* Wb      = (unsigned short*)(ws + 4554752);    // 4,096 us
    unsigned short* Gb      = (unsigned short*)(ws + 4556800);    // 135,168 us
    unsigned short* G2b     = (unsigned short*)(ws + 4624384);    // 4,325,376 us
    float*          cfs     = ws + 6787072;                       // 131,072 f
    float*          att     = ws + 6918144;                       // 131,072 f
    unsigned short* nattb   = (unsigned short*)(ws + 7049216);    // 131,072 us
    float*          cmatT   = ws + 7114752;                       // 135,168 f
    float*          zpart   = ws + 7249920;                       // 131,072 f
    // total 7,380,992 floats (~29.5 MB)

    // conversions
    conv_bf16<<<4096, 256, 0, stream>>>(x, xb, 512, 2000, 2048);
    conv_bf16<<<8192, 256, 0, stream>>>(fc_in_W, fcinWb, 1024, 2000, 2048);
    conv_bf16<<<512, 256, 0, stream>>>(fc1_W, fc1Wb, 128, 1024, 1024);
    conv_bf16<<<16, 256, 0, stream>>>(ntW, Wb, 64, 64, 64);
    conv_permW<<<2048, 256, 0, stream>>>(out1_W, out1WbT);
    conv_tgw<<<17424, 256, 0, stream>>>(tgw, Gb, G2b);

    // batch-independent attention-coefficient path
    coef_kernel<<<4096, 64, 0, stream>>>(coef_m, cW, cB, cattW, cfs);
    att_kernel<<<64, 256, 0, stream>>>(cfs, oattW, att);
    natt_new<<<128, 256, 0, stream>>>(ntW, att, nattb);

    // trunk MLP (bf16 MFMA)
    gemm_mfma<<<dim3(16, 8, 4), 256, 0, stream>>>(xb, 2048, fcinWb, 2048,
        h1p, nullptr, 1024, 524288L, nullptr, 0, 512);
    reduce_partials<<<2048, 256, 0, stream>>>(h1p, nullptr, h1b, 524288, 4,
        524288L, fc_in_b, 1023, 1);
    gemm_mfma<<<dim3(2, 8, 4), 256, 0, stream>>>(h1b, 1024, fc1Wb, 1024,
        h2p, nullptr, 128, 65536L, nullptr, 0, 256);
    reduce_partials<<<256, 256, 0, stream>>>(h2p, nullptr, h2b, 65536, 4,
        65536L, fc1_b, 127, 1);
    // out1: emits hbT = bf16 relu(h3+b) transposed per b (weights pre-permuted)
    gemm_mfma<<<dim3(64, 8, 1), 256, 0, stream>>>(h2b, 128, out1WbT, 128,
        nullptr, hbT, 4096, 0L, out1_b, 2, 128);

    // cmatT[e,o] = sum_d G2b[e,d]*natt[o,d]   (bf16 MFMA, k-split 8, transposed)
    gemm_mfma<<<dim3(1, 33, 8), 256, 0, stream>>>(G2b, 2048, nattb, 2048,
        cpT, nullptr, 64, 135168L, nullptr, 0, 256);
    reduce_partials<<<528, 256, 0, stream>>>(cpT, cmatT, nullptr, 135168, 8,
        135168L, nullptr, 0, 0);

    // fused nt1 + final (e-split into 4 partials) + finish
    final_part<<<dim3(512, 4), 256, 0, stream>>>(hbT, Wb, Gb, cmatT, outW, zpart);
    finish_kernel<<<128, 256, 0, stream>>>(zpart, outB, preluA, out);
}

// Round 5
// 234.408 us; speedup vs baseline: 2.7432x; 1.1021x over previous
//
#include <hip/hip_runtime.h>
#include <math.h>

typedef __attribute__((ext_vector_type(8))) short bf16x8;
typedef __attribute__((ext_vector_type(4))) float f32x4;

static __device__ __forceinline__ float fast_elu(float x) {
    return x > 0.0f ? x : __expf(x) - 1.0f;
}

static __device__ __forceinline__ unsigned short f2bf(float f) {
    unsigned int u = __float_as_uint(f);
    unsigned int r = (u + 0x7FFFu + ((u >> 16) & 1u)) >> 16;
    return (unsigned short)r;
}

// ---------------------------------------------------------------------------
// One mega conversion kernel: all f32 -> bf16 jobs in a single launch.
// ---------------------------------------------------------------------------
#define CV0 1048576   // xb          [512,2048 pad from 2000]
#define CV1 3145728   // fcinWb      [1024,2048 pad]
#define CV2 3276800   // fc1Wb       [128,1024]
#define CV3 3280896   // Wb          [64,64]
#define CV4 3805184   // out1WbT     [4096,128] row-permuted
#define CV5 8265728   // Gb/G2b split of tgw [2112,2112]
__global__ __launch_bounds__(256) void conv_all(
    const float* __restrict__ x, const float* __restrict__ fcinW,
    const float* __restrict__ fc1W, const float* __restrict__ ntW,
    const float* __restrict__ out1W, const float* __restrict__ tgw,
    unsigned short* __restrict__ xb, unsigned short* __restrict__ fcinWb,
    unsigned short* __restrict__ fc1Wb, unsigned short* __restrict__ Wb,
    unsigned short* __restrict__ out1WbT,
    unsigned short* __restrict__ Gb, unsigned short* __restrict__ G2b)
{
    int idx = blockIdx.x * 256 + threadIdx.x;
    if (idx < CV0) {
        int r = idx >> 11, k = idx & 2047;
        xb[idx] = (k < 2000) ? f2bf(x[(size_t)r * 2000 + k]) : (unsigned short)0;
    } else if (idx < CV1) {
        int i = idx - CV0;
        int r = i >> 11, k = i & 2047;
        fcinWb[i] = (k < 2000) ? f2bf(fcinW[(size_t)r * 2000 + k]) : (unsigned short)0;
    } else if (idx < CV2) {
        int i = idx - CV1;
        fc1Wb[i] = f2bf(fc1W[i]);
    } else if (idx < CV3) {
        int i = idx - CV2;
        Wb[i] = f2bf(ntW[i]);
    } else if (idx < CV4) {
        int i = idx - CV3;
        int n = i >> 7, k = i & 127, d = n >> 6, p = n & 63;
        out1WbT[i] = f2bf(out1W[(size_t)((p << 6) | d) * 128 + k]);
    } else if (idx < CV5) {
        int i = idx - CV4;
        int e = i / 2112, k = i - e * 2112;
        unsigned short v = f2bf(tgw[(size_t)e * 2112 + k]);
        if (k < 64) Gb[e * 64 + k] = v;
        else        G2b[(size_t)e * 2048 + (k - 64)] = v;
    }
}

// ---------------------------------------------------------------------------
// Generic bf16 MFMA GEMM-BT with software-pipelined staging.
// C[m,n] = sum_k A[m,k]*B[n,k]. 64x64 tiles. grid (N/64, M/64, z).
// mode 0: f32 partial -> C + bz*strideCz
// mode 2: bf16 relu(acc+bias[perm(n)]) -> Cb
// ---------------------------------------------------------------------------
__global__ __launch_bounds__(256) void gemm_mfma(
    const unsigned short* __restrict__ A, int lda,
    const unsigned short* __restrict__ B, int ldb,
    float* __restrict__ C, unsigned short* __restrict__ Cb,
    int ldc, long strideCz,
    const float* __restrict__ bias, int mode, int kchunk)
{
    __shared__ __align__(16) unsigned short As[64 * 40];
    __shared__ __align__(16) unsigned short Bs[64 * 40];
    const int t = threadIdx.x;
    const int w = t >> 6, lane = t & 63, l16 = lane & 15, quad = lane >> 4;
    const int n0 = blockIdx.x * 64, m0 = blockIdx.y * 64;
    const int kb0 = blockIdx.z * kchunk;
    const int r = t >> 2, koff = (t & 3) * 8;
    if (mode == 0) C += (size_t)blockIdx.z * strideCz;

    const size_t arow = (size_t)(m0 + r) * lda + koff;
    const size_t brow = (size_t)(n0 + r) * ldb + koff;
    bf16x8 av = *reinterpret_cast<const bf16x8*>(&A[arow + kb0]);
    bf16x8 bv = *reinterpret_cast<const bf16x8*>(&B[brow + kb0]);

    f32x4 acc[4] = {};
    for (int kb = kb0; kb < kb0 + kchunk; kb += 32) {
        __syncthreads();
        *reinterpret_cast<bf16x8*>(&As[r * 40 + koff]) = av;
        *reinterpret_cast<bf16x8*>(&Bs[r * 40 + koff]) = bv;
        if (kb + 32 < kb0 + kchunk) {   // prefetch next chunk (overlaps MFMA)
            av = *reinterpret_cast<const bf16x8*>(&A[arow + kb + 32]);
            bv = *reinterpret_cast<const bf16x8*>(&B[brow + kb + 32]);
        }
        __syncthreads();
        bf16x8 af = *reinterpret_cast<const bf16x8*>(&As[(w * 16 + l16) * 40 + quad * 8]);
        #pragma unroll
        for (int nt = 0; nt < 4; ++nt) {
            bf16x8 bf = *reinterpret_cast<const bf16x8*>(&Bs[(nt * 16 + l16) * 40 + quad * 8]);
            acc[nt] = __builtin_amdgcn_mfma_f32_16x16x32_bf16(af, bf, acc[nt], 0, 0, 0);
        }
    }
    #pragma unroll
    for (int nt = 0; nt < 4; ++nt)
        #pragma unroll
        for (int i = 0; i < 4; ++i) {
            int m = m0 + w * 16 + quad * 4 + i;
            int n = n0 + nt * 16 + l16;
            if (mode == 0) {
                C[(size_t)m * ldc + n] = acc[nt][i];
            } else {
                int bidx = (((n & 63) << 6) | (n >> 6));
                float v = acc[nt][i] + bias[bidx];
                v = fmaxf(v, 0.0f);
                Cb[(size_t)m * ldc + n] = f2bf(v);
            }
        }
}

// dst = act( sum_j src[i + j*pstride] + bias[i & biasMask] ); f32 or bf16 out
__global__ __launch_bounds__(256) void reduce_partials(
    const float* __restrict__ src, float* __restrict__ dstF,
    unsigned short* __restrict__ dstB, int n,
    int nparts, long pstride, const float* __restrict__ bias, int biasMask, int doRelu)
{
    int i = blockIdx.x * 256 + threadIdx.x;
    if (i >= n) return;
    float a = 0.0f;
    for (int j = 0; j < nparts; ++j) a += src[i + (long)j * pstride];
    if (bias) a += bias[i & biasMask];
    if (doRelu) a = fmaxf(a, 0.0f);
    if (dstB) dstB[i] = f2bf(a); else dstF[i] = a;
}

// ---------------------------------------------------------------------------
// Coef pipeline part 1: 4 (x,y) pairs per 256-thread block (1 per wave)
// ---------------------------------------------------------------------------
__global__ __launch_bounds__(256) void coef_kernel(
    const float* __restrict__ coef_m,   // [64,64,8]
    const float* __restrict__ cW,       // [8,32]
    const float* __restrict__ cB,       // [8,32]
    const float* __restrict__ attW,     // [8,32,32]
    float* __restrict__ cfs)            // [64,64,32]
{
    __shared__ float cf_s[4][256];
    __shared__ float part[4][64];
    const int t = threadIdx.x;
    const int wv = t >> 6, lane = t & 63;
    const int xy = blockIdx.x * 4 + wv;
    float ls = 0.0f;
    #pragma unroll
    for (int i = 0; i < 4; ++i) {
        int idx = i * 64 + lane;
        int f = idx >> 5;
        float v = fast_elu(coef_m[xy * 8 + f] * cW[idx] + cB[idx]);
        cf_s[wv][idx] = v;
        ls += __expf(fast_elu(v));
    }
    #pragma unroll
    for (int m = 1; m < 64; m <<= 1) ls += __shfl_xor(ls, m, 64);
    __syncthreads();
    const float rs = __builtin_amdgcn_rcpf(ls);
    const int g = lane & 31, fg = lane >> 5;
    float acc = 0.0f;
    for (int f = fg * 4; f < fg * 4 + 4; ++f) {
        float lin = 0.0f;
        #pragma unroll
        for (int h = 0; h < 32; h += 4) {
            float4 Lv = *reinterpret_cast<const float4*>(&cf_s[wv][f * 32 + h]);
            float4 Wv = *reinterpret_cast<const float4*>(&attW[f * 1024 + g * 32 + h]);
            lin += Lv.x * Wv.x + Lv.y * Wv.y + Lv.z * Wv.z + Lv.w * Wv.w;
        }
        float e = __expf(fast_elu(cf_s[wv][f * 32 + g]));
        acc += fast_elu(e * lin * rs);
    }
    part[wv][lane] = acc;
    __syncthreads();
    if (lane < 32) {
        float tot = part[wv][lane] + part[wv][lane + 32];
        cfs[xy * 32 + lane] = fast_elu(tot * 0.125f);
    }
}

// ---------------------------------------------------------------------------
// Coef pipeline part 2: node attention -> att[o, i*32+g], block 1024
// ---------------------------------------------------------------------------
__global__ __launch_bounds__(1024) void att_kernel(
    const float* __restrict__ cfs,     // [64,64,32]
    const float* __restrict__ oattW,   // [64,32,32]
    float* __restrict__ att)           // [64,2048]
{
    __shared__ float L[2048];
    __shared__ float red[1024];
    __shared__ float csum[32];
    const int t = threadIdx.x;
    const int o = blockIdx.x;
    L[t] = cfs[o * 2048 + t];
    L[t + 1024] = cfs[o * 2048 + 1024 + t];
    __syncthreads();
    {
        int h = t & 31, ig = t >> 5;
        red[t] = __expf(fast_elu(L[(2 * ig) * 32 + h])) +
                 __expf(fast_elu(L[(2 * ig + 1) * 32 + h]));
        __syncthreads();
        if (t < 32) {
            float cs = 0.0f;
            #pragma unroll
            for (int j = 0; j < 32; ++j) cs += red[j * 32 + t];
            csum[t] = cs;
        }
        __syncthreads();
    }
    #pragma unroll
    for (int j = 0; j < 2; ++j) {
        int idx = t + 1024 * j;
        int i = idx >> 5, g = idx & 31;
        float lin2 = 0.0f;
        #pragma unroll
        for (int h = 0; h < 32; h += 4) {
            float4 Lv = *reinterpret_cast<const float4*>(&L[i * 32 + h]);
            float4 Wv = *reinterpret_cast<const float4*>(&oattW[i * 1024 + g * 32 + h]);
            lin2 += Lv.x * Wv.x + Lv.y * Wv.y + Lv.z * Wv.z + Lv.w * Wv.w;
        }
        float p2 = __expf(fast_elu(L[idx])) * __builtin_amdgcn_rcpf(csum[g]);
        att[o * 2048 + idx] = p2 * lin2;
    }
}

// ---------------------------------------------------------------------------
// nattb[o,d] = bf16( sum_p ntW[o,p] * att[p,d] )  grid 128 (d-tiles of 16)
// ---------------------------------------------------------------------------
__global__ __launch_bounds__(256) void natt_new(
    const float* __restrict__ ntW,   // [64,64]
    const float* __restrict__ att,   // [64,2048]
    unsigned short* __restrict__ nattb) // [64,2048] bf16
{
    __shared__ float ntW_s[64 * 65];
    __shared__ float att_s[64 * 17];
    const int t = threadIdx.x;
    const int d0 = blockIdx.x * 16;
    #pragma unroll
    for (int j = 0; j < 16; ++j) {
        int idx = t + 256 * j;
        ntW_s[(idx >> 6) * 65 + (idx & 63)] = ntW[idx];
    }
    #pragma unroll
    for (int j = 0; j < 4; ++j) {
        int idx = t + 256 * j;
        int p = idx >> 4, dd = idx & 15;
        att_s[p * 17 + dd] = att[p * 2048 + d0 + dd];
    }
    __syncthreads();
    const int dd = t & 15, ob = (t >> 4) * 4;
    float acc[4] = {0.0f, 0.0f, 0.0f, 0.0f};
    for (int p = 0; p < 64; ++p) {
        float av = att_s[p * 17 + dd];
        #pragma unroll
        for (int i = 0; i < 4; ++i) acc[i] += ntW_s[(ob + i) * 65 + p] * av;
    }
    #pragma unroll
    for (int i = 0; i < 4; ++i)
        nattb[(ob + i) * 2048 + d0 + dd] = f2bf(acc[i]);
}

// ---------------------------------------------------------------------------
// Final fused kernel (e-split, software-pipelined):
// nt1 = ntW x relu-hidden (MFMA), then for ec in {z, z+4,...}:
// S = nt1·G^T (+ cmatT as MFMA C-operand); zpart += sigmoid(S)*w[e]
// grid (512, 4), block 256 = 4 waves
// ---------------------------------------------------------------------------
__global__ __launch_bounds__(256) void final_part(
    const unsigned short* __restrict__ hbT,  // [512][4096] bf16, idx d*64+p
    const unsigned short* __restrict__ Wb,   // [64,64] bf16 (ntW)
    const unsigned short* __restrict__ Gb,   // [2112,64] bf16
    const float* __restrict__ cmatT,  // [2112,64]
    const float* __restrict__ outW,   // [2112]
    float* __restrict__ zpart)        // [4][512][64]
{
    __shared__ __align__(16) unsigned short HtT[64 * 72];   // [d][p]
    __shared__ __align__(16) unsigned short nt1_s[64 * 72]; // [o][d]
    __shared__ float zp[4][64];
    const int t = threadIdx.x;
    const int w = t >> 6;
    const int lane = t & 63;
    const int l16 = lane & 15, quad = lane >> 4;
    const int b = blockIdx.x;
    const int z = blockIdx.y;

    // stage hbT row b -> LDS [d][p]
    const unsigned short* src = hbT + (size_t)b * 4096;
    #pragma unroll
    for (int j = 0; j < 2; ++j) {
        int c = t + j * 256;
        *reinterpret_cast<bf16x8*>(&HtT[(c >> 3) * 72 + (c & 7) * 8]) =
            *reinterpret_cast<const bf16x8*>(&src[c * 8]);
    }
    __syncthreads();

    // nt1 tiles: wave w owns o-rows [w*16,+16), all 4 d-tiles
    bf16x8 aW[2];
    #pragma unroll
    for (int h = 0; h < 2; ++h)
        aW[h] = *reinterpret_cast<const bf16x8*>(&Wb[(w * 16 + l16) * 64 + h * 32 + quad * 8]);
    #pragma unroll
    for (int dt = 0; dt < 4; ++dt) {
        f32x4 acc = {0.0f, 0.0f, 0.0f, 0.0f};
        #pragma unroll
        for (int h = 0; h < 2; ++h) {
            bf16x8 bf = *reinterpret_cast<const bf16x8*>(
                &HtT[(dt * 16 + l16) * 72 + h * 32 + quad * 8]);
            acc = __builtin_amdgcn_mfma_f32_16x16x32_bf16(aW[h], bf, acc, 0, 0, 0);
        }
        #pragma unroll
        for (int i = 0; i < 4; ++i)
            nt1_s[(w * 16 + quad * 4 + i) * 72 + dt * 16 + l16] = f2bf(acc[i]);
    }
    __syncthreads();

    // A-fragments of nt1 for the e-loop
    bf16x8 afr[4][2];
    #pragma unroll
    for (int ot = 0; ot < 4; ++ot)
        #pragma unroll
        for (int h = 0; h < 2; ++h)
            afr[ot][h] = *reinterpret_cast<const bf16x8*>(
                &nt1_s[(ot * 16 + l16) * 72 + h * 32 + quad * 8]);

    // software-pipelined e-loop
    float zacc[4][4] = {};
    int e = z * 64 + w * 16 + l16;
    bf16x8 g0 = *reinterpret_cast<const bf16x8*>(&Gb[(size_t)e * 64 + quad * 8]);
    bf16x8 g1 = *reinterpret_cast<const bf16x8*>(&Gb[(size_t)e * 64 + 32 + quad * 8]);
    float wv = outW[e];
    float4 c4[4];
    #pragma unroll
    for (int ot = 0; ot < 4; ++ot)
        c4[ot] = *reinterpret_cast<const float4*>(&cmatT[(size_t)e * 64 + ot * 16 + quad * 4]);

    for (int ec = z; ec < 33; ec += 4) {
        const int en = e + 256;
        const bool more = (ec + 4 < 33);
        bf16x8 ng0, ng1; float4 nc4[4]; float nwv;
        if (more) {   // prefetch next iteration (overlaps MFMA+epilogue below)
            ng0 = *reinterpret_cast<const bf16x8*>(&Gb[(size_t)en * 64 + quad * 8]);
            ng1 = *reinterpret_cast<const bf16x8*>(&Gb[(size_t)en * 64 + 32 + quad * 8]);
            nwv = outW[en];
            #pragma unroll
            for (int ot = 0; ot < 4; ++ot)
                nc4[ot] = *reinterpret_cast<const float4*>(
                    &cmatT[(size_t)en * 64 + ot * 16 + quad * 4]);
        }
        #pragma unroll
        for (int ot = 0; ot < 4; ++ot) {
            f32x4 acc = {c4[ot].x, c4[ot].y, c4[ot].z, c4[ot].w};
            acc = __builtin_amdgcn_mfma_f32_16x16x32_bf16(afr[ot][0], g0, acc, 0, 0, 0);
            acc = __builtin_amdgcn_mfma_f32_16x16x32_bf16(afr[ot][1], g1, acc, 0, 0, 0);
            #pragma unroll
            for (int i = 0; i < 4; ++i) {
                float sg = __builtin_amdgcn_rcpf(1.0f + __expf(-acc[i]));
                zacc[ot][i] += sg * wv;
            }
        }
        if (more) {
            g0 = ng0; g1 = ng1; wv = nwv;
            #pragma unroll
            for (int ot = 0; ot < 4; ++ot) c4[ot] = nc4[ot];
        }
        e = en;
    }
    #pragma unroll
    for (int m = 1; m < 16; m <<= 1)
        #pragma unroll
        for (int ot = 0; ot < 4; ++ot)
            #pragma unroll
            for (int i = 0; i < 4; ++i)
                zacc[ot][i] += __shfl_xor(zacc[ot][i], m, 64);

    if (l16 == 0) {
        #pragma unroll
        for (int ot = 0; ot < 4; ++ot)
            #pragma unroll
            for (int i = 0; i < 4; ++i)
                zp[w][ot * 16 + quad * 4 + i] = zacc[ot][i];
    }
    __syncthreads();
    if (t < 64)
        zpart[((size_t)z * 512 + b) * 64 + t] = zp[0][t] + zp[1][t] + zp[2][t] + zp[3][t];
}

// out[i] = prelu( sum_z zpart[z][i] + outB )
__global__ __launch_bounds__(256) void finish_kernel(
    const float* __restrict__ zpart, const float* __restrict__ outB,
    const float* __restrict__ preluA, float* __restrict__ out)
{
    int i = blockIdx.x * 256 + threadIdx.x;  // < 32768
    float z = zpart[i] + zpart[32768 + i] + zpart[65536 + i] + zpart[98304 + i] + outB[0];
    float pa = preluA[0];
    out[i] = (z >= 0.0f) ? z : pa * z;
}

extern "C" void kernel_launch(void* const* d_in, const int* in_sizes, int n_in,
                              void* d_out, int out_size, void* d_ws, size_t ws_size,
                              hipStream_t stream)
{
    const float* x       = (const float*)d_in[0];
    const float* fc_in_W = (const float*)d_in[1];
    const float* fc_in_b = (const float*)d_in[2];
    const float* fc1_W   = (const float*)d_in[3];
    const float* fc1_b   = (const float*)d_in[4];
    const float* out1_W  = (const float*)d_in[5];
    const float* out1_b  = (const float*)d_in[6];
    const float* cW      = (const float*)d_in[7];
    const float* cB      = (const float*)d_in[8];
    const float* cattW   = (const float*)d_in[9];
    const float* oattW   = (const float*)d_in[10];
    const float* ntW     = (const float*)d_in[11];
    const float* tgw     = (const float*)d_in[12];
    const float* outW    = (const float*)d_in[13];
    const float* outB    = (const float*)d_in[14];
    const float* preluA  = (const float*)d_in[15];
    const float* coef_m  = (const float*)d_in[16];
    float* out = (float*)d_out;
    float* ws  = (float*)d_ws;

    // workspace layout (float offsets); aliased regions are stream-ordered
    unsigned short* xb      = (unsigned short*)(ws + 0);          // 1,048,576 us
    unsigned short* fcinWb  = (unsigned short*)(ws + 524288);     // 2,097,152 us
    float*          cpT     = ws + 0;                             // 8*135168 f (after fc_in)
    float*          h1p     = ws + 1572864;                       // 2,097,152 f
    unsigned short* hbT     = (unsigned short*)(ws + 1572864);    // 2,097,152 us (after h1p dead)
    unsigned short* h1b     = (unsigned short*)(ws + 3670016);    // 524,288 us
    unsigned short* fc1Wb   = (unsigned short*)(ws + 3932160);    // 131,072 us
    float*          h2p     = ws + 3997696;                       // 524,288 f (8 partials)
    float*          zpart   = ws + 3997696;                       // 131,072 f (after h2p dead)
    unsigned short* h2b     = (unsigned short*)(ws + 4521984);    // 65,536 us
    unsigned short* out1WbT = (unsigned short*)(ws + 4554752);    // 524,288 us
    unsigned short* Wb      = (unsigned short*)(ws + 4816896);    // 4,096 us
    unsigned short* Gb      = (unsigned short*)(ws + 4818944);    // 135,168 us
    unsigned short* G2b     = (unsigned short*)(ws + 4886528);    // 4,325,376 us
    float*          cfs     = ws + 7049216;                       // 131,072 f
    float*          att     = ws + 7180288;                       // 131,072 f
    unsigned short* nattb   = (unsigned short*)(ws + 7311360);    // 131,072 us
    float*          cmatT   = ws + 7376896;                       // 135,168 f
    // total 7,512,064 floats (~30.0 MB)

    // all f32->bf16 conversions in one launch
    conv_all<<<(CV5 + 255) / 256, 256, 0, stream>>>(
        x, fc_in_W, fc1_W, ntW, out1_W, tgw,
        xb, fcinWb, fc1Wb, Wb, out1WbT, Gb, G2b);

    // batch-independent attention-coefficient path
    coef_kernel<<<1024, 256, 0, stream>>>(coef_m, cW, cB, cattW, cfs);
    att_kernel<<<64, 1024, 0, stream>>>(cfs, oattW, att);
    natt_new<<<128, 256, 0, stream>>>(ntW, att, nattb);

    // trunk MLP (bf16 MFMA)
    gemm_mfma<<<dim3(16, 8, 4), 256, 0, stream>>>(xb, 2048, fcinWb, 2048,
        h1p, nullptr, 1024, 524288L, nullptr, 0, 512);
    reduce_partials<<<2048, 256, 0, stream>>>(h1p, nullptr, h1b, 524288, 4,
        524288L, fc_in_b, 1023, 1);
    gemm_mfma<<<dim3(2, 8, 8), 256, 0, stream>>>(h1b, 1024, fc1Wb, 1024,
        h2p, nullptr, 128, 65536L, nullptr, 0, 128);
    reduce_partials<<<256, 256, 0, stream>>>(h2p, nullptr, h2b, 65536, 8,
        65536L, fc1_b, 127, 1);
    // out1: emits hbT = bf16 relu(h3+b) transposed per b (weights pre-permuted)
    gemm_mfma<<<dim3(64, 8, 1), 256, 0, stream>>>(h2b, 128, out1WbT, 128,
        nullptr, hbT, 4096, 0L, out1_b, 2, 128);

    // cmatT[e,o] = sum_d G2b[e,d]*natt[o,d]   (bf16 MFMA, k-split 8, transposed)
    gemm_mfma<<<dim3(1, 33, 8), 256, 0, stream>>>(G2b, 2048, nattb, 2048,
        cpT, nullptr, 64, 135168L, nullptr, 0, 256);
    reduce_partials<<<528, 256, 0, stream>>>(cpT, cmatT, nullptr, 135168, 8,
        135168L, nullptr, 0, 0);

    // fused nt1 + final (e-split into 4 partials) + finish
    final_part<<<dim3(512, 4), 256, 0, stream>>>(hbT, Wb, Gb, cmatT, outW, zpart);
    finish_kernel<<<128, 256, 0, stream>>>(zpart, outB, preluA, out);
}